// Round 1
// baseline (6094.614 us; speedup 1.0000x reference)
//
#include <hip/hip_runtime.h>
#include <hip/hip_bf16.h>
#include <math.h>

#define WDIM 64
#define HWN 4096      // 64*64
#define DCH 256
#define EPSV 1e-5f

// ---------------- conv 3x3, pad 1 (NCHW, OIHW) ----------------
// block: 256 thr = 64 w-lanes x 4 h-quads; each thread computes 4 vertical outputs.
template<int CIN>
__global__ __launch_bounds__(256) void conv3x3_k(const float* __restrict__ in,
    const float* __restrict__ wgt, float* __restrict__ out) {
  const int w  = threadIdx.x & 63;
  const int hq = threadIdx.x >> 6;
  const int h0 = blockIdx.x * 16 + hq * 4;
  const int cout = blockIdx.y;
  const int b    = blockIdx.z;
  const int Cout = gridDim.y;
  const float* inb = in + (size_t)b * CIN * HWN;
  const float* wp0 = wgt + (size_t)cout * CIN * 9;
  float a0 = 0.f, a1 = 0.f, a2 = 0.f, a3 = 0.f;
  const bool topok = (h0 > 0);
  const bool botok = (h0 + 4 < 64);
  for (int ci = 0; ci < CIN; ++ci) {
    const float* ip = inb + (size_t)ci * HWN;
    const float* wp = wp0 + ci * 9;
#pragma unroll
    for (int kx = 0; kx < 3; ++kx) {
      const int wc = w + kx - 1;
      const bool wok = ((unsigned)wc < 64u);
      const float* cp = ip + wc;
      float r0 = (wok && topok) ? cp[(h0 - 1) * 64] : 0.f;
      float r1 = wok ? cp[(h0    ) * 64] : 0.f;
      float r2 = wok ? cp[(h0 + 1) * 64] : 0.f;
      float r3 = wok ? cp[(h0 + 2) * 64] : 0.f;
      float r4 = wok ? cp[(h0 + 3) * 64] : 0.f;
      float r5 = (wok && botok) ? cp[(h0 + 4) * 64] : 0.f;
      const float w0 = wp[kx], w1 = wp[kx + 3], w2 = wp[kx + 6];
      a0 = fmaf(w2, r2, fmaf(w1, r1, fmaf(w0, r0, a0)));
      a1 = fmaf(w2, r3, fmaf(w1, r2, fmaf(w0, r1, a1)));
      a2 = fmaf(w2, r4, fmaf(w1, r3, fmaf(w0, r2, a2)));
      a3 = fmaf(w2, r5, fmaf(w1, r4, fmaf(w0, r3, a3)));
    }
  }
  float* op = out + (((size_t)(b * Cout + cout)) * 64 + h0) * 64 + w;
  op[0] = a0; op[64] = a1; op[128] = a2; op[192] = a3;
}

// ---------------- precompute A = sc^2, B = cw*sc^2 (interleaved float2) ----------------
template<int K>
__global__ __launch_bounds__(256) void prep_k(const float* __restrict__ sc,
    const float* __restrict__ cw, float2* __restrict__ AB) {
  int idx = blockIdx.x * 256 + threadIdx.x;   // grid = K blocks -> idx < 256*K
  int d = idx / K, k = idx % K;
  float s = sc[idx];            // sc layout [d][k] contiguous
  float a = s * s;
  AB[idx] = make_float2(a, cw[k * DCH + d] * a);
}

template<int K>
__global__ void ck_k(const float* __restrict__ sc, const float* __restrict__ cw,
                     float* __restrict__ Ck) {
  int k = threadIdx.x;
  if (k < K) {
    float s = 0.f;
    for (int d = 0; d < DCH; ++d) {
      float t = cw[k * DCH + d] * sc[d * K + k];
      s = fmaf(t, t, s);
    }
    Ck[k] = s;
  }
}

// ---------------- scores + softmax -> Qt[b][k][n] ----------------
template<int K>
__global__ __launch_bounds__(256) void score_k(const float* __restrict__ X,
    const float2* __restrict__ AB, const float* __restrict__ Ck,
    float* __restrict__ Qt) {
  const int b = blockIdx.y;
  const int n = blockIdx.x * 256 + threadIdx.x;
  const float* xp = X + ((size_t)b * DCH) * HWN + n;
  float s_[K];
#pragma unroll
  for (int k = 0; k < K; ++k) s_[k] = 0.f;
  for (int d = 0; d < DCH; ++d) {
    float xv = xp[(size_t)d * HWN];
    float x2 = xv * xv;
    float xm = -2.f * xv;
    const float2* abp = AB + d * K;
#pragma unroll
    for (int k = 0; k < K; ++k) {
      float2 ab = abp[k];
      s_[k] = fmaf(x2, ab.x, s_[k]);
      s_[k] = fmaf(xm, ab.y, s_[k]);
    }
  }
  float mx = -1e30f;
#pragma unroll
  for (int k = 0; k < K; ++k) { s_[k] = -0.5f * (s_[k] + Ck[k]); mx = fmaxf(mx, s_[k]); }
  float sum = 0.f;
#pragma unroll
  for (int k = 0; k < K; ++k) { float e = expf(s_[k] - mx); s_[k] = e; sum += e; }
  float inv = 1.f / sum;
#pragma unroll
  for (int k = 0; k < K; ++k) Qt[((size_t)(b * K + k)) * HWN + n] = s_[k] * inv;
}

// ---------------- Qs[b][k] = sum_n Qt ----------------
__global__ __launch_bounds__(256) void qsum_k(const float* __restrict__ Qt,
    float* __restrict__ Qs, int K) {
  int k = blockIdx.x, b = blockIdx.y;
  const float* qp = Qt + ((size_t)(b * K + k)) * HWN;
  float s = 0.f;
  for (int n = threadIdx.x; n < HWN; n += 256) s += qp[n];
  __shared__ float red[4];
  for (int off = 32; off; off >>= 1) s += __shfl_down(s, off);
  int lane = threadIdx.x & 63, wid = threadIdx.x >> 6;
  if (lane == 0) red[wid] = s;
  __syncthreads();
  if (threadIdx.x == 0) Qs[b * K + k] = red[0] + red[1] + red[2] + red[3];
}

// ---------------- M[b][d][k] = sum_n X[b][d][n] * Qt[b][k][n] ----------------
__global__ __launch_bounds__(256) void mmul_k(const float* __restrict__ X,
    const float* __restrict__ Qt, float* __restrict__ M, int K) {
  __shared__ float4 xr4[HWN / 4];
  __shared__ float red[4];
  float* xr = (float*)xr4;
  const int d = blockIdx.x, b = blockIdx.y;
  const float4* xp4 = (const float4*)(X + ((size_t)(b * DCH + d)) * HWN);
  for (int i = threadIdx.x; i < HWN / 4; i += 256) xr4[i] = xp4[i];
  __syncthreads();
  const int lane = threadIdx.x & 63, wid = threadIdx.x >> 6;
  for (int k = 0; k < K; ++k) {
    const float* qp = Qt + ((size_t)(b * K + k)) * HWN;
    float s = 0.f;
    for (int n = threadIdx.x; n < HWN; n += 256) s = fmaf(xr[n], qp[n], s);
    for (int off = 32; off; off >>= 1) s += __shfl_down(s, off);
    if (lane == 0) red[wid] = s;
    __syncthreads();
    if (threadIdx.x == 0) M[((size_t)(b * DCH + d)) * K + k] = red[0] + red[1] + red[2] + red[3];
    __syncthreads();
  }
}

// ---------------- Z from M, Qs; L2-normalize over d ----------------
template<int K>
__global__ __launch_bounds__(256) void zbuild_k(const float* __restrict__ M,
    const float* __restrict__ Qs, const float* __restrict__ sc,
    const float* __restrict__ cw, float* __restrict__ Z) {
  __shared__ float zl[DCH * K];
  __shared__ float rn[K];
  const int b = blockIdx.x, d = threadIdx.x;
#pragma unroll
  for (int k = 0; k < K; ++k) {
    float qs = Qs[b * K + k];
    float m  = M[((size_t)(b * DCH + d)) * K + k];
    float z  = sc[d * K + k] * (m - cw[k * DCH + d] * qs) / qs;
    zl[d * K + k] = z;
  }
  __syncthreads();
  if (d < K) {
    float s = 0.f;
    for (int i = 0; i < DCH; ++i) { float v = zl[i * K + d]; s = fmaf(v, v, s); }
    rn[d] = 1.f / sqrtf(s);
  }
  __syncthreads();
#pragma unroll
  for (int k = 0; k < K; ++k)
    Z[((size_t)(b * DCH + d)) * K + k] = zl[d * K + k] * rn[k];
}

// ---------------- graph conv: adj, support, out, relu ----------------
template<int K>
__global__ __launch_bounds__(256) void graph1_k(const float* __restrict__ Z,
    const float* __restrict__ Wm, float* __restrict__ Graw) {
  __shared__ float zl[DCH * K];
  __shared__ float adj[K * K];
  const int b = blockIdx.x, t = threadIdx.x;
  for (int i = t; i < DCH * K; i += 256) zl[i] = Z[(size_t)b * DCH * K + i];
  __syncthreads();
  for (int p = t; p < K * K; p += 256) {
    int k = p / K, l = p % K;
    float s = 0.f;
    for (int i = 0; i < DCH; ++i) s = fmaf(zl[i * K + k], zl[i * K + l], s);
    adj[p] = s;
  }
  __syncthreads();
  float sup[K];
#pragma unroll
  for (int k = 0; k < K; ++k) sup[k] = 0.f;
  const float* wr = Wm + (size_t)t * DCH;
  for (int j = 0; j < DCH; ++j) {
    float wv = wr[j];
#pragma unroll
    for (int k = 0; k < K; ++k) sup[k] = fmaf(wv, zl[j * K + k], sup[k]);
  }
#pragma unroll
  for (int l = 0; l < K; ++l) {
    float s = 0.f;
#pragma unroll
    for (int k = 0; k < K; ++k) s = fmaf(sup[k], adj[k * K + l], s);
    Graw[((size_t)(b * DCH + t)) * K + l] = fmaxf(s, 0.f);
  }
}

// ---------------- BN1d over (b, l) per channel d ----------------
template<int K>
__global__ __launch_bounds__(256) void graph2_k(const float* __restrict__ Graw,
    const float* __restrict__ gamma, const float* __restrict__ beta,
    float* __restrict__ G) {
  const int d = threadIdx.x;
  float s = 0.f, ss = 0.f;
#pragma unroll
  for (int b = 0; b < 2; ++b)
#pragma unroll
    for (int l = 0; l < K; ++l) {
      float v = Graw[((size_t)(b * DCH + d)) * K + l];
      s += v; ss = fmaf(v, v, ss);
    }
  const float invn = 1.f / (2 * K);
  float mean = s * invn;
  float var  = ss * invn - mean * mean;
  float giv  = gamma[d] / sqrtf(var + EPSV);
  float be   = beta[d];
#pragma unroll
  for (int b = 0; b < 2; ++b)
#pragma unroll
    for (int l = 0; l < K; ++l) {
      float v = Graw[((size_t)(b * DCH + d)) * K + l];
      G[((size_t)(b * DCH + d)) * K + l] = fmaf(v - mean, giv, be);
    }
}

// ---------------- EG[b][o][k] = sum_d ext[o][d] * G[b][d][k] ----------------
template<int K>
__global__ __launch_bounds__(256) void eg_k(const float* __restrict__ E,
    const float* __restrict__ G, float* __restrict__ EG) {
  __shared__ float gl[DCH * K];
  const int b = blockIdx.x, t = threadIdx.x;
  for (int i = t; i < DCH * K; i += 256) gl[i] = G[(size_t)b * DCH * K + i];
  __syncthreads();
  float a1[K], a2[K];
#pragma unroll
  for (int k = 0; k < K; ++k) { a1[k] = 0.f; a2[k] = 0.f; }
  const float* e1 = E + (size_t)t * DCH;
  const float* e2 = E + (size_t)(t + 256) * DCH;
  for (int d = 0; d < DCH; ++d) {
    float v1 = e1[d], v2 = e2[d];
#pragma unroll
    for (int k = 0; k < K; ++k) {
      a1[k] = fmaf(v1, gl[d * K + k], a1[k]);
      a2[k] = fmaf(v2, gl[d * K + k], a2[k]);
    }
  }
#pragma unroll
  for (int k = 0; k < K; ++k) {
    EG[((size_t)(b * 512 + t)) * K + k] = a1[k];
    EG[((size_t)(b * 512 + t + 256)) * K + k] = a2[k];
  }
}

// ---------------- Y = EG @ Qt + c -> concat buffer ----------------
template<int K>
__global__ __launch_bounds__(256) void yout_k(const float* __restrict__ EG,
    const float* __restrict__ Qt, const float* __restrict__ cres,
    float* __restrict__ cat, int coff) {
  const int n = blockIdx.x * 256 + threadIdx.x;
  const int o = blockIdx.y, b = blockIdx.z;
  float y = cres[((size_t)(b * 512 + o)) * HWN + n];
  const float* eg = EG + ((size_t)(b * 512 + o)) * K;
#pragma unroll
  for (int k = 0; k < K; ++k)
    y = fmaf(eg[k], Qt[((size_t)(b * K + k)) * HWN + n], y);
  cat[((size_t)(b * 1536 + coff + o)) * HWN + n] = y;
}

// ---------------- smooth BN stats ----------------
__global__ __launch_bounds__(256) void bnstat_k(const float* __restrict__ out,
    float* __restrict__ stat) {
  const int o = blockIdx.x;
  float s = 0.f, ss = 0.f;
  for (int i = threadIdx.x; i < 2 * HWN; i += 256) {
    int b = i >> 12, n = i & (HWN - 1);
    float v = out[((size_t)(b * 512 + o)) * HWN + n];
    s += v; ss = fmaf(v, v, ss);
  }
  __shared__ float rs[4], rss[4];
  for (int off = 32; off; off >>= 1) { s += __shfl_down(s, off); ss += __shfl_down(ss, off); }
  int lane = threadIdx.x & 63, wid = threadIdx.x >> 6;
  if (lane == 0) { rs[wid] = s; rss[wid] = ss; }
  __syncthreads();
  if (threadIdx.x == 0) {
    float S = rs[0] + rs[1] + rs[2] + rs[3];
    float SS = rss[0] + rss[1] + rss[2] + rss[3];
    float mean = S / (2 * HWN);
    float var  = SS / (2 * HWN) - mean * mean;
    stat[o] = mean;
    stat[512 + o] = 1.f / sqrtf(var + EPSV);
  }
}

__global__ __launch_bounds__(256) void bnrelu_k(float* __restrict__ out,
    const float* __restrict__ stat, const float* __restrict__ g,
    const float* __restrict__ bb) {
  int idx = blockIdx.x * 256 + threadIdx.x;
  int o = (idx >> 12) & 511;
  float v = out[idx];
  float r = fmaf((v - stat[o]) * stat[512 + o], g[o], bb[o]);
  out[idx] = fmaxf(r, 0.f);
}

// ---------------- branch driver ----------------
template<int K>
static void run_branch(const float* cin, void* const* din, float* cat, int coff,
                       float* X, float* Qt, float* Qs, float* Ck, float* Mb,
                       float* Zb, float* Graw, float* G, float* EG, float2* AB,
                       hipStream_t stream) {
  const float* convw = (const float*)din[0];
  const float* cw    = (const float*)din[1];
  const float* sc    = (const float*)din[2];
  const float* gcnw  = (const float*)din[3];
  const float* bng   = (const float*)din[4];
  const float* bnb   = (const float*)din[5];
  const float* extw  = (const float*)din[6];
  conv3x3_k<512><<<dim3(4, 256, 2), 256, 0, stream>>>(cin, convw, X);
  prep_k<K><<<K, 256, 0, stream>>>(sc, cw, AB);
  ck_k<K><<<1, 256, 0, stream>>>(sc, cw, Ck);
  score_k<K><<<dim3(16, 2), 256, 0, stream>>>(X, AB, Ck, Qt);
  qsum_k<<<dim3(K, 2), 256, 0, stream>>>(Qt, Qs, K);
  mmul_k<<<dim3(256, 2), 256, 0, stream>>>(X, Qt, Mb, K);
  zbuild_k<K><<<2, 256, 0, stream>>>(Mb, Qs, sc, cw, Zb);
  graph1_k<K><<<2, 256, 0, stream>>>(Zb, gcnw, Graw);
  graph2_k<K><<<1, 256, 0, stream>>>(Graw, bng, bnb, G);
  eg_k<K><<<2, 256, 0, stream>>>(extw, G, EG);
  yout_k<K><<<dim3(16, 512, 2), 256, 0, stream>>>(EG, Qt, cin, cat, coff);
}

extern "C" void kernel_launch(void* const* d_in, const int* in_sizes, int n_in,
                              void* d_out, int out_size, void* d_ws, size_t ws_size,
                              hipStream_t stream) {
  const float* c3 = (const float*)d_in[0];
  const float* c4 = (const float*)d_in[1];
  const float* c5 = (const float*)d_in[2];
  const float* smooth_w = (const float*)d_in[24];
  const float* smg = (const float*)d_in[25];
  const float* smb = (const float*)d_in[26];
  float* dout = (float*)d_out;

  float* ws  = (float*)d_ws;
  float* cat = ws;                        // 2*1536*4096 = 12,582,912
  float* X   = cat + 12582912;            // 2*256*4096  =  2,097,152
  float* Qt  = X + 2097152;               // 2*32*4096   =    262,144
  float* Qs  = Qt + 262144;               // 64
  float* Ck  = Qs + 64;                   // 32
  float* Mb  = Ck + 32;                   // 16384
  float* Zb  = Mb + 16384;                // 16384
  float* Graw = Zb + 16384;               // 16384
  float* G   = Graw + 16384;              // 16384
  float* EG  = G + 16384;                 // 32768
  float* ABf = EG + 32768;                // 16384 (float2 area)
  float* stat = ABf + 16384;              // 1024
  float2* AB = (float2*)ABf;

  // concat order: [x_8(c5), x_16(c4), x_32(c3)]
  run_branch<8>(c5, d_in + 17, cat, 0,    X, Qt, Qs, Ck, Mb, Zb, Graw, G, EG, AB, stream);
  run_branch<16>(c4, d_in + 10, cat, 512, X, Qt, Qs, Ck, Mb, Zb, Graw, G, EG, AB, stream);
  run_branch<32>(c3, d_in + 3, cat, 1024, X, Qt, Qs, Ck, Mb, Zb, Graw, G, EG, AB, stream);

  // smooth conv -> raw d_out, then BN2d + relu
  conv3x3_k<1536><<<dim3(4, 512, 2), 256, 0, stream>>>(cat, smooth_w, dout);
  bnstat_k<<<512, 256, 0, stream>>>(dout, stat);
  bnrelu_k<<<16384, 256, 0, stream>>>(dout, stat, smg, smb);
}

// Round 2
// 2084.202 us; speedup vs baseline: 2.9242x; 2.9242x over previous
//
#include <hip/hip_runtime.h>
#include <hip/hip_bf16.h>
#include <math.h>

#define HWN 4096      // 64*64
#define DCH 256
#define EPSV 1e-5f

typedef unsigned short u16;
typedef __attribute__((ext_vector_type(8))) short short8b;   // 8 bf16 payload
typedef __attribute__((ext_vector_type(4))) float fx4;
typedef __attribute__((ext_vector_type(8))) unsigned short u16x8;
typedef __attribute__((ext_vector_type(4))) int i32x4;

static __device__ inline u16 f2bf(float f) {
  __hip_bfloat16 h = __float2bfloat16(f);
  return *reinterpret_cast<u16*>(&h);
}
static __device__ inline float bf2f(u16 u) {
  unsigned int v = ((unsigned int)u) << 16;
  return __uint_as_float(v);
}

// ---------------- NCHW f32 -> NHWC bf16 transpose (C=512) ----------------
__global__ __launch_bounds__(256) void transpose_k(const float* __restrict__ in,
    u16* __restrict__ out, int C) {
  __shared__ float tl[64][65];
  const int n0 = blockIdx.x * 64, c0 = blockIdx.y * 64, b = blockIdx.z;
  const int t = threadIdx.x;
  const float* ip = in + ((size_t)(b * C + c0)) * HWN + n0;
#pragma unroll
  for (int i = 0; i < 4; ++i) {
    int cr = (t >> 4) + i * 16, nc = (t & 15) * 4;
    float4 v = *(const float4*)(ip + (size_t)cr * HWN + nc);
    tl[cr][nc] = v.x; tl[cr][nc + 1] = v.y; tl[cr][nc + 2] = v.z; tl[cr][nc + 3] = v.w;
  }
  __syncthreads();
  u16* op = out + ((size_t)(b * HWN + n0)) * C + c0;
#pragma unroll
  for (int i = 0; i < 4; ++i) {
    int nr = (t >> 4) + i * 16, cc = (t & 15) * 4;
    ushort4 u;
    u.x = f2bf(tl[cc][nr]); u.y = f2bf(tl[cc + 1][nr]);
    u.z = f2bf(tl[cc + 2][nr]); u.w = f2bf(tl[cc + 3][nr]);
    *(ushort4*)(op + (size_t)nr * C + cc) = u;
  }
}

// ---------------- conv weights OIHW f32 -> [tap][co][ci] bf16 ----------------
__global__ __launch_bounds__(256) void wprep_k(const float* __restrict__ w,
    u16* __restrict__ wb, int CIN, int COUT) {
  int idx = blockIdx.x * 256 + threadIdx.x;
  int co = idx / CIN, ci = idx % CIN;
  const float* wp = w + (size_t)idx * 9;
#pragma unroll
  for (int tap = 0; tap < 9; ++tap)
    wb[((size_t)tap * COUT + co) * CIN + ci] = f2bf(wp[tap]);
}

// ---------------- MFMA conv 3x3 pad 1 ----------------
// xt: NHWC bf16 [B][64][64][CIN]; wb: [9][COUT][CIN] bf16; out: NCHW f32.
// Block tile: NROWS image rows (N = NROWS*64 pixels) x 128 cout. NWAVES waves,
// wave tile 16 pixels x 128 cout. LDS holds NROWS+2 halo rows x 66 (w-pad) x 32 ci.
template<int CIN, int COUT, int NROWS, int NWAVES>
__global__ __launch_bounds__(NWAVES * 64) void convmfma_k(
    const u16* __restrict__ xt, const u16* __restrict__ wb,
    float* __restrict__ out) {
  constexpr int R = NROWS + 2;
  constexpr int COTILES = COUT / 128;
  __shared__ u16 lds[R * 66 * 32];

  // XCD-aware decode: 256 blocks = 8 xcd-groups x 32
  const int flat = blockIdx.x;
  const int xcd = flat & 7, j = flat >> 3;
  const int cot = xcd % COTILES;
  const int nt = (xcd / COTILES) * 32 + j;
  const int b = nt / (64 / NROWS);
  const int h0 = (nt % (64 / NROWS)) * NROWS;

  const int t = threadIdx.x;
  const int wv = t >> 6, lane = t & 63;
  const int h_loc = wv >> 2, w0 = (wv & 3) * 16;
  const int m = lane & 15, kg = lane >> 4;

  fx4 acc[8];
#pragma unroll
  for (int i = 0; i < 8; ++i) acc[i] = (fx4){0.f, 0.f, 0.f, 0.f};

  const int s_hr = t >> 6, s_w = t & 63;   // stage pair (valid if t < R*64)
  const int pidx = t - R * 64;             // pad id (valid if 0 <= pidx < R*8)

#pragma unroll 1
  for (int ci0 = 0; ci0 < CIN; ci0 += 32) {
    __syncthreads();
    if (t < R * 64) {
      const int hg = h0 - 1 + s_hr;
      const int rowid = s_hr * 66 + 1 + s_w;
      if ((unsigned)hg < 64u) {
        const u16* gp = xt + ((size_t)(b * HWN + hg * 64 + s_w)) * CIN + ci0;
#pragma unroll
        for (int g4 = 0; g4 < 4; ++g4) {
          int g = rowid * 4 + g4; g ^= (g >> 2) & 7;
          *reinterpret_cast<i32x4*>(&lds[g * 8]) =
              *reinterpret_cast<const i32x4*>(gp + g4 * 8);
        }
      } else {
#pragma unroll
        for (int g4 = 0; g4 < 4; ++g4) {
          int g = rowid * 4 + g4; g ^= (g >> 2) & 7;
          *reinterpret_cast<i32x4*>(&lds[g * 8]) = (i32x4){0, 0, 0, 0};
        }
      }
    } else if (pidx >= 0 && pidx < R * 8) {
      int r = pidx >> 3, side = (pidx >> 2) & 1, g4 = pidx & 3;
      int g = (r * 66 + (side ? 65 : 0)) * 4 + g4; g ^= (g >> 2) & 7;
      *reinterpret_cast<i32x4*>(&lds[g * 8]) = (i32x4){0, 0, 0, 0};
    }
    __syncthreads();

    const u16* wbase = wb + ((size_t)(cot * 128 + m)) * CIN + ci0 + kg * 8;
#pragma unroll
    for (int tap = 0; tap < 9; ++tap) {
      const int ty = tap / 3, tx = tap % 3;
      // A fragment: input pixels (LDS, swizzled)
      int rowid = (h_loc + ty) * 66 + w0 + m + tx;
      int g = rowid * 4 + kg; g ^= (g >> 2) & 7;
      short8b afrag = *reinterpret_cast<const short8b*>(&lds[g * 8]);
      // B fragments: weights (global/L2)
      const u16* wtap = wbase + (size_t)tap * COUT * CIN;
      short8b bfr[8];
#pragma unroll
      for (int cof = 0; cof < 8; ++cof)
        bfr[cof] = *reinterpret_cast<const short8b*>(wtap + (size_t)cof * 16 * CIN);
#pragma unroll
      for (int cof = 0; cof < 8; ++cof)
        acc[cof] = __builtin_amdgcn_mfma_f32_16x16x32_bf16(afrag, bfr[cof], acc[cof], 0, 0, 0);
    }
  }

  // epilogue: D row = pixel = (lane>>4)*4+reg, col = cout = lane&15
  const int h = h0 + h_loc;
  const int wout = w0 + kg * 4;
#pragma unroll
  for (int cof = 0; cof < 8; ++cof) {
    int co = cot * 128 + cof * 16 + m;
    float* op = out + (((size_t)(b * COUT + co)) * 64 + h) * 64 + wout;
    *reinterpret_cast<fx4*>(op) = acc[cof];
  }
}

// ---------------- precompute A = sc^2, B = cw*sc^2 (interleaved float2) ----------------
template<int K>
__global__ __launch_bounds__(256) void prep_k(const float* __restrict__ sc,
    const float* __restrict__ cw, float2* __restrict__ AB) {
  int idx = blockIdx.x * 256 + threadIdx.x;
  int d = idx / K, k = idx % K;
  float s = sc[idx];
  float a = s * s;
  AB[idx] = make_float2(a, cw[k * DCH + d] * a);
}

template<int K>
__global__ void ck_k(const float* __restrict__ sc, const float* __restrict__ cw,
                     float* __restrict__ Ck) {
  int k = threadIdx.x;
  if (k < K) {
    float s = 0.f;
    for (int d = 0; d < DCH; ++d) {
      float t = cw[k * DCH + d] * sc[d * K + k];
      s = fmaf(t, t, s);
    }
    Ck[k] = s;
  }
}

// ---------------- scores + softmax -> Qt[b][k][n] ----------------
template<int K>
__global__ __launch_bounds__(256) void score_k(const float* __restrict__ X,
    const float2* __restrict__ AB, const float* __restrict__ Ck,
    float* __restrict__ Qt) {
  const int b = blockIdx.y;
  const int n = blockIdx.x * 256 + threadIdx.x;
  const float* xp = X + ((size_t)b * DCH) * HWN + n;
  float s_[K];
#pragma unroll
  for (int k = 0; k < K; ++k) s_[k] = 0.f;
  for (int d = 0; d < DCH; ++d) {
    float xv = xp[(size_t)d * HWN];
    float x2 = xv * xv;
    float xm = -2.f * xv;
    const float2* abp = AB + d * K;
#pragma unroll
    for (int k = 0; k < K; ++k) {
      float2 ab = abp[k];
      s_[k] = fmaf(x2, ab.x, s_[k]);
      s_[k] = fmaf(xm, ab.y, s_[k]);
    }
  }
  float mx = -1e30f;
#pragma unroll
  for (int k = 0; k < K; ++k) { s_[k] = -0.5f * (s_[k] + Ck[k]); mx = fmaxf(mx, s_[k]); }
  float sum = 0.f;
#pragma unroll
  for (int k = 0; k < K; ++k) { float e = expf(s_[k] - mx); s_[k] = e; sum += e; }
  float inv = 1.f / sum;
#pragma unroll
  for (int k = 0; k < K; ++k) Qt[((size_t)(b * K + k)) * HWN + n] = s_[k] * inv;
}

// ---------------- Qs[b][k] = sum_n Qt ----------------
__global__ __launch_bounds__(256) void qsum_k(const float* __restrict__ Qt,
    float* __restrict__ Qs, int K) {
  int k = blockIdx.x, b = blockIdx.y;
  const float* qp = Qt + ((size_t)(b * K + k)) * HWN;
  float s = 0.f;
  for (int n = threadIdx.x; n < HWN; n += 256) s += qp[n];
  __shared__ float red[4];
  for (int off = 32; off; off >>= 1) s += __shfl_down(s, off);
  int lane = threadIdx.x & 63, wid = threadIdx.x >> 6;
  if (lane == 0) red[wid] = s;
  __syncthreads();
  if (threadIdx.x == 0) Qs[b * K + k] = red[0] + red[1] + red[2] + red[3];
}

// ---------------- M[b][d][k] = sum_n X[b][d][n] * Qt[b][k][n] ----------------
__global__ __launch_bounds__(256) void mmul_k(const float* __restrict__ X,
    const float* __restrict__ Qt, float* __restrict__ M, int K) {
  __shared__ float4 xr4[HWN / 4];
  __shared__ float red[4];
  float* xr = (float*)xr4;
  const int d = blockIdx.x, b = blockIdx.y;
  const float4* xp4 = (const float4*)(X + ((size_t)(b * DCH + d)) * HWN);
  for (int i = threadIdx.x; i < HWN / 4; i += 256) xr4[i] = xp4[i];
  __syncthreads();
  const int lane = threadIdx.x & 63, wid = threadIdx.x >> 6;
  for (int k = 0; k < K; ++k) {
    const float* qp = Qt + ((size_t)(b * K + k)) * HWN;
    float s = 0.f;
    for (int n = threadIdx.x; n < HWN; n += 256) s = fmaf(xr[n], qp[n], s);
    for (int off = 32; off; off >>= 1) s += __shfl_down(s, off);
    if (lane == 0) red[wid] = s;
    __syncthreads();
    if (threadIdx.x == 0) M[((size_t)(b * DCH + d)) * K + k] = red[0] + red[1] + red[2] + red[3];
    __syncthreads();
  }
}

// ---------------- Z from M, Qs; L2-normalize over d ----------------
template<int K>
__global__ __launch_bounds__(256) void zbuild_k(const float* __restrict__ M,
    const float* __restrict__ Qs, const float* __restrict__ sc,
    const float* __restrict__ cw, float* __restrict__ Z) {
  __shared__ float zl[DCH * K];
  __shared__ float rn[K];
  const int b = blockIdx.x, d = threadIdx.x;
#pragma unroll
  for (int k = 0; k < K; ++k) {
    float qs = Qs[b * K + k];
    float mm = M[((size_t)(b * DCH + d)) * K + k];
    float z  = sc[d * K + k] * (mm - cw[k * DCH + d] * qs) / qs;
    zl[d * K + k] = z;
  }
  __syncthreads();
  if (d < K) {
    float s = 0.f;
    for (int i = 0; i < DCH; ++i) { float v = zl[i * K + d]; s = fmaf(v, v, s); }
    rn[d] = 1.f / sqrtf(s);
  }
  __syncthreads();
#pragma unroll
  for (int k = 0; k < K; ++k)
    Z[((size_t)(b * DCH + d)) * K + k] = zl[d * K + k] * rn[k];
}

// ---------------- graph conv: adj, support, out, relu ----------------
template<int K>
__global__ __launch_bounds__(256) void graph1_k(const float* __restrict__ Z,
    const float* __restrict__ Wm, float* __restrict__ Graw) {
  __shared__ float zl[DCH * K];
  __shared__ float adj[K * K];
  const int b = blockIdx.x, t = threadIdx.x;
  for (int i = t; i < DCH * K; i += 256) zl[i] = Z[(size_t)b * DCH * K + i];
  __syncthreads();
  for (int p = t; p < K * K; p += 256) {
    int k = p / K, l = p % K;
    float s = 0.f;
    for (int i = 0; i < DCH; ++i) s = fmaf(zl[i * K + k], zl[i * K + l], s);
    adj[p] = s;
  }
  __syncthreads();
  float sup[K];
#pragma unroll
  for (int k = 0; k < K; ++k) sup[k] = 0.f;
  const float* wr = Wm + (size_t)t * DCH;
  for (int jj = 0; jj < DCH; ++jj) {
    float wv = wr[jj];
#pragma unroll
    for (int k = 0; k < K; ++k) sup[k] = fmaf(wv, zl[jj * K + k], sup[k]);
  }
#pragma unroll
  for (int l = 0; l < K; ++l) {
    float s = 0.f;
#pragma unroll
    for (int k = 0; k < K; ++k) s = fmaf(sup[k], adj[k * K + l], s);
    Graw[((size_t)(b * DCH + t)) * K + l] = fmaxf(s, 0.f);
  }
}

// ---------------- BN1d over (b, l) per channel d ----------------
template<int K>
__global__ __launch_bounds__(256) void graph2_k(const float* __restrict__ Graw,
    const float* __restrict__ gamma, const float* __restrict__ beta,
    float* __restrict__ G) {
  const int d = threadIdx.x;
  float s = 0.f, ss = 0.f;
#pragma unroll
  for (int b = 0; b < 2; ++b)
#pragma unroll
    for (int l = 0; l < K; ++l) {
      float v = Graw[((size_t)(b * DCH + d)) * K + l];
      s += v; ss = fmaf(v, v, ss);
    }
  const float invn = 1.f / (2 * K);
  float mean = s * invn;
  float var  = ss * invn - mean * mean;
  float giv  = gamma[d] / sqrtf(var + EPSV);
  float be   = beta[d];
#pragma unroll
  for (int b = 0; b < 2; ++b)
#pragma unroll
    for (int l = 0; l < K; ++l) {
      float v = Graw[((size_t)(b * DCH + d)) * K + l];
      G[((size_t)(b * DCH + d)) * K + l] = fmaf(v - mean, giv, be);
    }
}

// ---------------- EG[b][o][k] = sum_d ext[o][d] * G[b][d][k] ----------------
template<int K>
__global__ __launch_bounds__(256) void eg_k(const float* __restrict__ E,
    const float* __restrict__ G, float* __restrict__ EG) {
  __shared__ float gl[DCH * K];
  const int b = blockIdx.x, t = threadIdx.x;
  for (int i = t; i < DCH * K; i += 256) gl[i] = G[(size_t)b * DCH * K + i];
  __syncthreads();
  float a1[K], a2[K];
#pragma unroll
  for (int k = 0; k < K; ++k) { a1[k] = 0.f; a2[k] = 0.f; }
  const float* e1 = E + (size_t)t * DCH;
  const float* e2 = E + (size_t)(t + 256) * DCH;
  for (int d = 0; d < DCH; ++d) {
    float v1 = e1[d], v2 = e2[d];
#pragma unroll
    for (int k = 0; k < K; ++k) {
      a1[k] = fmaf(v1, gl[d * K + k], a1[k]);
      a2[k] = fmaf(v2, gl[d * K + k], a2[k]);
    }
  }
#pragma unroll
  for (int k = 0; k < K; ++k) {
    EG[((size_t)(b * 512 + t)) * K + k] = a1[k];
    EG[((size_t)(b * 512 + t + 256)) * K + k] = a2[k];
  }
}

// ---------------- Y = EG @ Qt + c -> NHWC bf16 cat ----------------
// egl LDS layout: [k][512co] bf16; all lanes of a cog read same addr (broadcast).
template<int K>
__global__ __launch_bounds__(256) void yout_nhwc_k(const float* __restrict__ EG,
    const float* __restrict__ Qt, const float* __restrict__ cres,
    u16* __restrict__ cat, int coff) {
  __shared__ u16 egl[K * 512];
  const int b = blockIdx.y;
  const int t = threadIdx.x;
  const int n = blockIdx.x * 64 + (t & 63);
  const int cog = t >> 6;
  for (int i = t; i < K * 512; i += 256) {
    int k = i / 512, co = i % 512;
    egl[i] = f2bf(EG[((size_t)(b * 512 + co)) * K + k]);
  }
  float q[K];
#pragma unroll
  for (int k = 0; k < K; ++k) q[k] = Qt[((size_t)(b * K + k)) * HWN + n];
  __syncthreads();
  u16* cp = cat + ((size_t)(b * HWN + n)) * 1536 + coff;
  const float* crow = cres + (size_t)b * 512 * HWN + n;
#pragma unroll 1
  for (int it = 0; it < 16; ++it) {
    int co = cog * 128 + it * 8;
    float y[8];
#pragma unroll
    for (int jj = 0; jj < 8; ++jj) y[jj] = crow[(size_t)(co + jj) * HWN];
#pragma unroll
    for (int k = 0; k < K; ++k) {
      u16x8 eg = *reinterpret_cast<const u16x8*>(&egl[k * 512 + co]);
#pragma unroll
      for (int jj = 0; jj < 8; ++jj) y[jj] = fmaf(bf2f(eg[jj]), q[k], y[jj]);
    }
    u16x8 o;
#pragma unroll
    for (int jj = 0; jj < 8; ++jj) o[jj] = f2bf(y[jj]);
    *reinterpret_cast<u16x8*>(cp + co) = o;
  }
}

// ---------------- smooth BN stats ----------------
__global__ __launch_bounds__(256) void bnstat_k(const float* __restrict__ out,
    float* __restrict__ stat) {
  const int o = blockIdx.x;
  float s = 0.f, ss = 0.f;
  for (int i = threadIdx.x; i < 2 * HWN; i += 256) {
    int b = i >> 12, n = i & (HWN - 1);
    float v = out[((size_t)(b * 512 + o)) * HWN + n];
    s += v; ss = fmaf(v, v, ss);
  }
  __shared__ float rs[4], rss[4];
  for (int off = 32; off; off >>= 1) { s += __shfl_down(s, off); ss += __shfl_down(ss, off); }
  int lane = threadIdx.x & 63, wid = threadIdx.x >> 6;
  if (lane == 0) { rs[wid] = s; rss[wid] = ss; }
  __syncthreads();
  if (threadIdx.x == 0) {
    float S = rs[0] + rs[1] + rs[2] + rs[3];
    float SS = rss[0] + rss[1] + rss[2] + rss[3];
    float mean = S / (2 * HWN);
    float var  = SS / (2 * HWN) - mean * mean;
    stat[o] = mean;
    stat[512 + o] = 1.f / sqrtf(var + EPSV);
  }
}

__global__ __launch_bounds__(256) void bnrelu_k(float* __restrict__ out,
    const float* __restrict__ stat, const float* __restrict__ g,
    const float* __restrict__ bb) {
  int idx = blockIdx.x * 256 + threadIdx.x;
  int o = (idx >> 12) & 511;
  float v = out[idx];
  float r = fmaf((v - stat[o]) * stat[512 + o], g[o], bb[o]);
  out[idx] = fmaxf(r, 0.f);
}

// ---------------- branch driver ----------------
template<int K>
static void run_branch(const float* cin, void* const* din, u16* cat, int coff,
                       u16* Xt, u16* Wb, float* X, float* Qt, float* Qs,
                       float* Ck, float* Mb, float* Zb, float* Graw, float* G,
                       float* EG, float2* AB, hipStream_t stream) {
  const float* convw = (const float*)din[0];
  const float* cw    = (const float*)din[1];
  const float* sc    = (const float*)din[2];
  const float* gcnw  = (const float*)din[3];
  const float* bng   = (const float*)din[4];
  const float* bnb   = (const float*)din[5];
  const float* extw  = (const float*)din[6];
  transpose_k<<<dim3(64, 8, 2), 256, 0, stream>>>(cin, Xt, 512);
  wprep_k<<<(256 * 512) / 256, 256, 0, stream>>>(convw, Wb, 512, 256);
  convmfma_k<512, 256, 1, 4><<<256, 256, 0, stream>>>(Xt, Wb, X);
  prep_k<K><<<K, 256, 0, stream>>>(sc, cw, AB);
  ck_k<K><<<1, 256, 0, stream>>>(sc, cw, Ck);
  score_k<K><<<dim3(16, 2), 256, 0, stream>>>(X, AB, Ck, Qt);
  qsum_k<<<dim3(K, 2), 256, 0, stream>>>(Qt, Qs, K);
  mmul_k<<<dim3(256, 2), 256, 0, stream>>>(X, Qt, Mb, K);
  zbuild_k<K><<<2, 256, 0, stream>>>(Mb, Qs, sc, cw, Zb);
  graph1_k<K><<<2, 256, 0, stream>>>(Zb, gcnw, Graw);
  graph2_k<K><<<1, 256, 0, stream>>>(Graw, bng, bnb, G);
  eg_k<K><<<2, 256, 0, stream>>>(extw, G, EG);
  yout_nhwc_k<K><<<dim3(64, 2), 256, 0, stream>>>(EG, Qt, cin, cat, coff);
}

extern "C" void kernel_launch(void* const* d_in, const int* in_sizes, int n_in,
                              void* d_out, int out_size, void* d_ws, size_t ws_size,
                              hipStream_t stream) {
  const float* c3 = (const float*)d_in[0];
  const float* c4 = (const float*)d_in[1];
  const float* c5 = (const float*)d_in[2];
  const float* smooth_w = (const float*)d_in[24];
  const float* smg = (const float*)d_in[25];
  const float* smb = (const float*)d_in[26];
  float* dout = (float*)d_out;

  char* wsb = (char*)d_ws;
  u16* cat = (u16*)wsb;                          // 25,165,824 B
  u16* Xt  = (u16*)(wsb + 25165824);             //  8,388,608 B
  u16* Wb  = (u16*)(wsb + 33554432);             // 14,155,776 B
  float* X  = (float*)(wsb + 47710208);          //  8,388,608 B
  float* Qt = (float*)(wsb + 56098816);          //  1,048,576 B
  float* sm = (float*)(wsb + 57147392);          // small pool
  float* Qs = sm;            // 64
  float* Ck = sm + 64;       // 32
  float* Mb = sm + 128;      // 16384
  float* Zb = Mb + 16384;    // 16384
  float* Graw = Zb + 16384;  // 16384
  float* G  = Graw + 16384;  // 16384
  float* EG = G + 16384;     // 32768
  float* ABf = EG + 32768;   // 16384
  float* stat = ABf + 16384; // 1024
  float2* AB = (float2*)ABf;

  // concat order: [x_8(c5), x_16(c4), x_32(c3)]
  run_branch<8>(c5, d_in + 17, cat, 0,    Xt, Wb, X, Qt, Qs, Ck, Mb, Zb, Graw, G, EG, AB, stream);
  run_branch<16>(c4, d_in + 10, cat, 512, Xt, Wb, X, Qt, Qs, Ck, Mb, Zb, Graw, G, EG, AB, stream);
  run_branch<32>(c3, d_in + 3, cat, 1024, Xt, Wb, X, Qt, Qs, Ck, Mb, Zb, Graw, G, EG, AB, stream);

  // smooth conv (cat NHWC bf16 -> dout NCHW f32), then BN2d + relu
  wprep_k<<<(512 * 1536) / 256, 256, 0, stream>>>(smooth_w, Wb, 1536, 512);
  convmfma_k<1536, 512, 2, 8><<<256, 512, 0, stream>>>(cat, Wb, dout);
  bnstat_k<<<512, 256, 0, stream>>>(dout, stat);
  bnrelu_k<<<16384, 256, 0, stream>>>(dout, stat, smg, smb);
}

// Round 3
// 1262.056 us; speedup vs baseline: 4.8291x; 1.6514x over previous
//
#include <hip/hip_runtime.h>
#include <hip/hip_bf16.h>
#include <math.h>

#define HWN 4096      // 64*64
#define DCH 256
#define EPSV 1e-5f

typedef unsigned short u16;
typedef __attribute__((ext_vector_type(8))) short short8b;   // 8 bf16 payload
typedef __attribute__((ext_vector_type(4))) float fx4;
typedef __attribute__((ext_vector_type(8))) unsigned short u16x8;

static __device__ inline u16 f2bf(float f) {
  __hip_bfloat16 h = __float2bfloat16(f);
  return *reinterpret_cast<u16*>(&h);
}
static __device__ inline float bf2f(u16 u) {
  unsigned int v = ((unsigned int)u) << 16;
  return __uint_as_float(v);
}

// ---------------- NCHW f32 -> CHWc bf16 (chunks of 32 ci) ----------------
// out[b][c/32][pix][32]
__global__ __launch_bounds__(256) void t_chwc_k(const float* __restrict__ in,
    u16* __restrict__ out, int C) {
  __shared__ float tl[32][257];
  const int p0 = blockIdx.x * 256, cic = blockIdx.y, b = blockIdx.z;
  const int t = threadIdx.x;
  const float* ip = in + ((size_t)(b * C + cic * 32)) * HWN + p0;
#pragma unroll
  for (int r = 0; r < 32; ++r) tl[r][t] = ip[(size_t)r * HWN + t];
  __syncthreads();
  u16* op = out + ((size_t)((b * (C / 32) + cic)) * HWN + p0 + t) * 32;
#pragma unroll
  for (int g = 0; g < 4; ++g) {
    u16x8 o;
#pragma unroll
    for (int j = 0; j < 8; ++j) o[j] = f2bf(tl[g * 8 + j][t]);
    *reinterpret_cast<u16x8*>(op + g * 8) = o;
  }
}

// ---------------- weights OIHW f32 -> fragment-packed bf16 ----------------
// packed[tap][cic][cog] is a 1KB block: entry (kg*16+m)*8+j = w[cog*16+m][cic*32+kg*8+j][tap]
__global__ __launch_bounds__(256) void wpack_k(const float* __restrict__ w,
    u16* __restrict__ wp, int CIN, int COUT) {
  int idx = blockIdx.x * 256 + threadIdx.x;   // (co, ci)
  int co = idx / CIN, ci = idx % CIN;
  const float* src = w + (size_t)idx * 9;
  int cic = ci >> 5, kg = (ci >> 3) & 3, j = ci & 7;
  int cog = co >> 4, m = co & 15;
  size_t base = ((size_t)cic * (COUT / 16) + cog) * 512 + kg * 128 + m * 8 + j;
  size_t tapstride = (size_t)(CIN / 32) * (COUT / 16) * 512;
#pragma unroll
  for (int tap = 0; tap < 9; ++tap)
    wp[tap * tapstride + base] = f2bf(src[tap]);
}

// ---------------- direct-load MFMA conv 3x3 pad 1 ----------------
// xt: CHWc bf16; wp: fragment-packed; out: NCHW f32.
// wave tile 32px x 64co; block = WPX x WCO waves (BPX = WPX*32 px, BCO = WCO*64 co)
template<int CIN, int COUT, int BPX, int BCO>
__global__ __launch_bounds__((BPX / 32) * (BCO / 64) * 64) void convdir_k(
    const u16* __restrict__ xt, const u16* __restrict__ wp,
    float* __restrict__ out) {
  constexpr int NCIC = CIN / 32;
  constexpr int WPX = BPX / 32;
  constexpr int NCO = COUT / BCO;
  // XCD-aware bijective swizzle (grid % 8 == 0)
  int bidx = blockIdx.x;
  const int cpx = (int)gridDim.x >> 3;
  bidx = (bidx & 7) * cpx + (bidx >> 3);
  const int cob = (bidx % NCO) * BCO;
  const int pxb = (bidx / NCO) * BPX;          // global pixel base
  const int b = pxb >> 12;
  const int prow0 = (pxb & 4095) >> 6;

  const int wv = threadIdx.x >> 6, lane = threadIdx.x & 63;
  const int pg = wv % WPX, cg = wv / WPX;
  const int prow = prow0 + (pg >> 1);          // wave's image row
  const int wseg = (pg & 1) * 32;              // w offset of wave's 32 px
  const int m = lane & 15, kg = lane >> 4;

  fx4 acc[2][4];
#pragma unroll
  for (int i = 0; i < 2; ++i)
#pragma unroll
    for (int jn = 0; jn < 4; ++jn) acc[i][jn] = (fx4){0.f, 0.f, 0.f, 0.f};

  const short8b zero8 = (short8b){0, 0, 0, 0, 0, 0, 0, 0};

#pragma unroll 1
  for (int cic = 0; cic < NCIC; ++cic) {
    const u16* xbase = xt + ((size_t)(b * NCIC + cic)) * HWN * 32;
#pragma unroll
    for (int ty = 0; ty < 3; ++ty) {
      const int hr = prow + ty - 1;            // wave-uniform
      if ((unsigned)hr < 64u) {
        const u16* rowp = xbase + (size_t)hr * 64 * 32 + kg * 8;
        short8b a[2][3];
#pragma unroll
        for (int mt = 0; mt < 2; ++mt)
#pragma unroll
          for (int tx = 0; tx < 3; ++tx) {
            int wi = wseg + mt * 16 + m + tx - 1;
            bool ok = ((unsigned)wi < 64u);
            int wc = ok ? wi : 0;
            short8b v = *reinterpret_cast<const short8b*>(rowp + wc * 32);
            a[mt][tx] = ok ? v : zero8;
          }
#pragma unroll
        for (int tx = 0; tx < 3; ++tx) {
          const int tap = ty * 3 + tx;
          const u16* wt = wp + (((size_t)tap * NCIC + cic) * (COUT / 16)
                                + (cob >> 4) + cg * 4) * 512 + lane * 8;
          short8b bb[4];
#pragma unroll
          for (int nt = 0; nt < 4; ++nt)
            bb[nt] = *reinterpret_cast<const short8b*>(wt + nt * 512);
#pragma unroll
          for (int nt = 0; nt < 4; ++nt) {
            acc[0][nt] = __builtin_amdgcn_mfma_f32_16x16x32_bf16(a[0][tx], bb[nt], acc[0][nt], 0, 0, 0);
            acc[1][nt] = __builtin_amdgcn_mfma_f32_16x16x32_bf16(a[1][tx], bb[nt], acc[1][nt], 0, 0, 0);
          }
        }
      }
    }
  }

  // epilogue: D row = pixel-in-16tile = kg*4+r, col = co-in-16 = m
  const int pixrow = prow * 64 + wseg;
#pragma unroll
  for (int mt = 0; mt < 2; ++mt)
#pragma unroll
    for (int nt = 0; nt < 4; ++nt) {
      int co = cob + cg * 64 + nt * 16 + m;
      float* op = out + ((size_t)(b * COUT + co)) * HWN + pixrow + mt * 16 + kg * 4;
      *reinterpret_cast<fx4*>(op) = acc[mt][nt];
    }
}

// ---------------- precompute A = sc^2, B = cw*sc^2 (interleaved float2) ----------------
template<int K>
__global__ __launch_bounds__(256) void prep_k(const float* __restrict__ sc,
    const float* __restrict__ cw, float2* __restrict__ AB) {
  int idx = blockIdx.x * 256 + threadIdx.x;
  int d = idx / K, k = idx % K;
  float s = sc[idx];
  float a = s * s;
  AB[idx] = make_float2(a, cw[k * DCH + d] * a);
}

template<int K>
__global__ void ck_k(const float* __restrict__ sc, const float* __restrict__ cw,
                     float* __restrict__ Ck) {
  int k = threadIdx.x;
  if (k < K) {
    float s = 0.f;
    for (int d = 0; d < DCH; ++d) {
      float t = cw[k * DCH + d] * sc[d * K + k];
      s = fmaf(t, t, s);
    }
    Ck[k] = s;
  }
}

// ---------------- scores + softmax -> Qt[b][k][n] ----------------
template<int K>
__global__ __launch_bounds__(256) void score_k(const float* __restrict__ X,
    const float2* __restrict__ AB, const float* __restrict__ Ck,
    float* __restrict__ Qt) {
  const int b = blockIdx.y;
  const int n = blockIdx.x * 256 + threadIdx.x;
  const float* xp = X + ((size_t)b * DCH) * HWN + n;
  float s_[K];
#pragma unroll
  for (int k = 0; k < K; ++k) s_[k] = 0.f;
  for (int d = 0; d < DCH; ++d) {
    float xv = xp[(size_t)d * HWN];
    float x2 = xv * xv;
    float xm = -2.f * xv;
    const float2* abp = AB + d * K;
#pragma unroll
    for (int k = 0; k < K; ++k) {
      float2 ab = abp[k];
      s_[k] = fmaf(x2, ab.x, s_[k]);
      s_[k] = fmaf(xm, ab.y, s_[k]);
    }
  }
  float mx = -1e30f;
#pragma unroll
  for (int k = 0; k < K; ++k) { s_[k] = -0.5f * (s_[k] + Ck[k]); mx = fmaxf(mx, s_[k]); }
  float sum = 0.f;
#pragma unroll
  for (int k = 0; k < K; ++k) { float e = expf(s_[k] - mx); s_[k] = e; sum += e; }
  float inv = 1.f / sum;
#pragma unroll
  for (int k = 0; k < K; ++k) Qt[((size_t)(b * K + k)) * HWN + n] = s_[k] * inv;
}

// ---------------- Qs[b][k] = sum_n Qt ----------------
__global__ __launch_bounds__(256) void qsum_k(const float* __restrict__ Qt,
    float* __restrict__ Qs, int K) {
  int k = blockIdx.x, b = blockIdx.y;
  const float* qp = Qt + ((size_t)(b * K + k)) * HWN;
  float s = 0.f;
  for (int n = threadIdx.x; n < HWN; n += 256) s += qp[n];
  __shared__ float red[4];
  for (int off = 32; off; off >>= 1) s += __shfl_down(s, off);
  int lane = threadIdx.x & 63, wid = threadIdx.x >> 6;
  if (lane == 0) red[wid] = s;
  __syncthreads();
  if (threadIdx.x == 0) Qs[b * K + k] = red[0] + red[1] + red[2] + red[3];
}

// ---------------- M[b][d][k] = sum_n X[b][d][n] * Qt[b][k][n] ----------------
__global__ __launch_bounds__(256) void mmul_k(const float* __restrict__ X,
    const float* __restrict__ Qt, float* __restrict__ M, int K) {
  __shared__ float4 xr4[HWN / 4];
  __shared__ float red[4];
  float* xr = (float*)xr4;
  const int d = blockIdx.x, b = blockIdx.y;
  const float4* xp4 = (const float4*)(X + ((size_t)(b * DCH + d)) * HWN);
  for (int i = threadIdx.x; i < HWN / 4; i += 256) xr4[i] = xp4[i];
  __syncthreads();
  const int lane = threadIdx.x & 63, wid = threadIdx.x >> 6;
  for (int k = 0; k < K; ++k) {
    const float* qp = Qt + ((size_t)(b * K + k)) * HWN;
    float s = 0.f;
    for (int n = threadIdx.x; n < HWN; n += 256) s = fmaf(xr[n], qp[n], s);
    for (int off = 32; off; off >>= 1) s += __shfl_down(s, off);
    if (lane == 0) red[wid] = s;
    __syncthreads();
    if (threadIdx.x == 0) M[((size_t)(b * DCH + d)) * K + k] = red[0] + red[1] + red[2] + red[3];
    __syncthreads();
  }
}

// ---------------- Z from M, Qs; L2-normalize over d ----------------
template<int K>
__global__ __launch_bounds__(256) void zbuild_k(const float* __restrict__ M,
    const float* __restrict__ Qs, const float* __restrict__ sc,
    const float* __restrict__ cw, float* __restrict__ Z) {
  __shared__ float zl[DCH * K];
  __shared__ float rn[K];
  const int b = blockIdx.x, d = threadIdx.x;
#pragma unroll
  for (int k = 0; k < K; ++k) {
    float qs = Qs[b * K + k];
    float mm = M[((size_t)(b * DCH + d)) * K + k];
    float z  = sc[d * K + k] * (mm - cw[k * DCH + d] * qs) / qs;
    zl[d * K + k] = z;
  }
  __syncthreads();
  if (d < K) {
    float s = 0.f;
    for (int i = 0; i < DCH; ++i) { float v = zl[i * K + d]; s = fmaf(v, v, s); }
    rn[d] = 1.f / sqrtf(s);
  }
  __syncthreads();
#pragma unroll
  for (int k = 0; k < K; ++k)
    Z[((size_t)(b * DCH + d)) * K + k] = zl[d * K + k] * rn[k];
}

// ---------------- graph conv: adj, support, out, relu ----------------
template<int K>
__global__ __launch_bounds__(256) void graph1_k(const float* __restrict__ Z,
    const float* __restrict__ Wm, float* __restrict__ Graw) {
  __shared__ float zl[DCH * K];
  __shared__ float adj[K * K];
  const int b = blockIdx.x, t = threadIdx.x;
  for (int i = t; i < DCH * K; i += 256) zl[i] = Z[(size_t)b * DCH * K + i];
  __syncthreads();
  for (int p = t; p < K * K; p += 256) {
    int k = p / K, l = p % K;
    float s = 0.f;
    for (int i = 0; i < DCH; ++i) s = fmaf(zl[i * K + k], zl[i * K + l], s);
    adj[p] = s;
  }
  __syncthreads();
  float sup[K];
#pragma unroll
  for (int k = 0; k < K; ++k) sup[k] = 0.f;
  const float* wr = Wm + (size_t)t * DCH;
  for (int jj = 0; jj < DCH; ++jj) {
    float wv = wr[jj];
#pragma unroll
    for (int k = 0; k < K; ++k) sup[k] = fmaf(wv, zl[jj * K + k], sup[k]);
  }
#pragma unroll
  for (int l = 0; l < K; ++l) {
    float s = 0.f;
#pragma unroll
    for (int k = 0; k < K; ++k) s = fmaf(sup[k], adj[k * K + l], s);
    Graw[((size_t)(b * DCH + t)) * K + l] = fmaxf(s, 0.f);
  }
}

// ---------------- BN1d over (b, l) per channel d ----------------
template<int K>
__global__ __launch_bounds__(256) void graph2_k(const float* __restrict__ Graw,
    const float* __restrict__ gamma, const float* __restrict__ beta,
    float* __restrict__ G) {
  const int d = threadIdx.x;
  float s = 0.f, ss = 0.f;
#pragma unroll
  for (int b = 0; b < 2; ++b)
#pragma unroll
    for (int l = 0; l < K; ++l) {
      float v = Graw[((size_t)(b * DCH + d)) * K + l];
      s += v; ss = fmaf(v, v, ss);
    }
  const float invn = 1.f / (2 * K);
  float mean = s * invn;
  float var  = ss * invn - mean * mean;
  float giv  = gamma[d] / sqrtf(var + EPSV);
  float be   = beta[d];
#pragma unroll
  for (int b = 0; b < 2; ++b)
#pragma unroll
    for (int l = 0; l < K; ++l) {
      float v = Graw[((size_t)(b * DCH + d)) * K + l];
      G[((size_t)(b * DCH + d)) * K + l] = fmaf(v - mean, giv, be);
    }
}

// ---------------- EG[b][o][k] = sum_d ext[o][d] * G[b][d][k] ----------------
template<int K>
__global__ __launch_bounds__(256) void eg_k(const float* __restrict__ E,
    const float* __restrict__ G, float* __restrict__ EG) {
  __shared__ float gl[DCH * K];
  const int b = blockIdx.x, t = threadIdx.x;
  for (int i = t; i < DCH * K; i += 256) gl[i] = G[(size_t)b * DCH * K + i];
  __syncthreads();
  float a1[K], a2[K];
#pragma unroll
  for (int k = 0; k < K; ++k) { a1[k] = 0.f; a2[k] = 0.f; }
  const float* e1 = E + (size_t)t * DCH;
  const float* e2 = E + (size_t)(t + 256) * DCH;
  for (int d = 0; d < DCH; ++d) {
    float v1 = e1[d], v2 = e2[d];
#pragma unroll
    for (int k = 0; k < K; ++k) {
      a1[k] = fmaf(v1, gl[d * K + k], a1[k]);
      a2[k] = fmaf(v2, gl[d * K + k], a2[k]);
    }
  }
#pragma unroll
  for (int k = 0; k < K; ++k) {
    EG[((size_t)(b * 512 + t)) * K + k] = a1[k];
    EG[((size_t)(b * 512 + t + 256)) * K + k] = a2[k];
  }
}

// ---------------- Y = EG @ Qt + c -> CHWc bf16 cat ----------------
template<int K>
__global__ __launch_bounds__(256) void yout_chwc_k(const float* __restrict__ EG,
    const float* __restrict__ Qt, const float* __restrict__ cres,
    u16* __restrict__ cat, int coff) {
  __shared__ u16 egl[K * 512];
  const int b = blockIdx.y;
  const int t = threadIdx.x;
  const int n = blockIdx.x * 64 + (t & 63);
  const int cog = t >> 6;
  for (int i = t; i < K * 512; i += 256) {
    int k = i / 512, co = i % 512;
    egl[i] = f2bf(EG[((size_t)(b * 512 + co)) * K + k]);
  }
  float q[K];
#pragma unroll
  for (int k = 0; k < K; ++k) q[k] = Qt[((size_t)(b * K + k)) * HWN + n];
  __syncthreads();
  const float* crow = cres + (size_t)b * 512 * HWN + n;
#pragma unroll 1
  for (int it = 0; it < 16; ++it) {
    int co = cog * 128 + it * 8;
    float y[8];
#pragma unroll
    for (int jj = 0; jj < 8; ++jj) y[jj] = crow[(size_t)(co + jj) * HWN];
#pragma unroll
    for (int k = 0; k < K; ++k) {
      u16x8 eg = *reinterpret_cast<const u16x8*>(&egl[k * 512 + co]);
#pragma unroll
      for (int jj = 0; jj < 8; ++jj) y[jj] = fmaf(bf2f(eg[jj]), q[k], y[jj]);
    }
    u16x8 o;
#pragma unroll
    for (int jj = 0; jj < 8; ++jj) o[jj] = f2bf(y[jj]);
    int ch = coff + co;
    *reinterpret_cast<u16x8*>(cat +
        (((size_t)(b * 48 + (ch >> 5)) * HWN + n) * 32 + (co & 31))) = o;
  }
}

// ---------------- smooth BN stats ----------------
__global__ __launch_bounds__(256) void bnstat_k(const float* __restrict__ out,
    float* __restrict__ stat) {
  const int o = blockIdx.x;
  float s = 0.f, ss = 0.f;
  for (int i = threadIdx.x; i < 2 * HWN; i += 256) {
    int b = i >> 12, n = i & (HWN - 1);
    float v = out[((size_t)(b * 512 + o)) * HWN + n];
    s += v; ss = fmaf(v, v, ss);
  }
  __shared__ float rs[4], rss[4];
  for (int off = 32; off; off >>= 1) { s += __shfl_down(s, off); ss += __shfl_down(ss, off); }
  int lane = threadIdx.x & 63, wid = threadIdx.x >> 6;
  if (lane == 0) { rs[wid] = s; rss[wid] = ss; }
  __syncthreads();
  if (threadIdx.x == 0) {
    float S = rs[0] + rs[1] + rs[2] + rs[3];
    float SS = rss[0] + rss[1] + rss[2] + rss[3];
    float mean = S / (2 * HWN);
    float var  = SS / (2 * HWN) - mean * mean;
    stat[o] = mean;
    stat[512 + o] = 1.f / sqrtf(var + EPSV);
  }
}

__global__ __launch_bounds__(256) void bnrelu_k(float* __restrict__ out,
    const float* __restrict__ stat, const float* __restrict__ g,
    const float* __restrict__ bb) {
  int idx = blockIdx.x * 256 + threadIdx.x;
  int o = (idx >> 12) & 511;
  float v = out[idx];
  float r = fmaf((v - stat[o]) * stat[512 + o], g[o], bb[o]);
  out[idx] = fmaxf(r, 0.f);
}

// ---------------- branch driver ----------------
template<int K>
static void run_branch(const float* cin, void* const* din, u16* cat, int coff,
                       u16* Xt, u16* Wb, float* X, float* Qt, float* Qs,
                       float* Ck, float* Mb, float* Zb, float* Graw, float* G,
                       float* EG, float2* AB, hipStream_t stream) {
  const float* convw = (const float*)din[0];
  const float* cw    = (const float*)din[1];
  const float* sc    = (const float*)din[2];
  const float* gcnw  = (const float*)din[3];
  const float* bng   = (const float*)din[4];
  const float* bnb   = (const float*)din[5];
  const float* extw  = (const float*)din[6];
  t_chwc_k<<<dim3(16, 16, 2), 256, 0, stream>>>(cin, Xt, 512);
  wpack_k<<<(256 * 512) / 256, 256, 0, stream>>>(convw, Wb, 512, 256);
  convdir_k<512, 256, 64, 128><<<256, 256, 0, stream>>>(Xt, Wb, X);
  prep_k<K><<<K, 256, 0, stream>>>(sc, cw, AB);
  ck_k<K><<<1, 256, 0, stream>>>(sc, cw, Ck);
  score_k<K><<<dim3(16, 2), 256, 0, stream>>>(X, AB, Ck, Qt);
  qsum_k<<<dim3(K, 2), 256, 0, stream>>>(Qt, Qs, K);
  mmul_k<<<dim3(256, 2), 256, 0, stream>>>(X, Qt, Mb, K);
  zbuild_k<K><<<2, 256, 0, stream>>>(Mb, Qs, sc, cw, Zb);
  graph1_k<K><<<2, 256, 0, stream>>>(Zb, gcnw, Graw);
  graph2_k<K><<<1, 256, 0, stream>>>(Graw, bng, bnb, G);
  eg_k<K><<<2, 256, 0, stream>>>(extw, G, EG);
  yout_chwc_k<K><<<dim3(64, 2), 256, 0, stream>>>(EG, Qt, cin, cat, coff);
}

extern "C" void kernel_launch(void* const* d_in, const int* in_sizes, int n_in,
                              void* d_out, int out_size, void* d_ws, size_t ws_size,
                              hipStream_t stream) {
  const float* c3 = (const float*)d_in[0];
  const float* c4 = (const float*)d_in[1];
  const float* c5 = (const float*)d_in[2];
  const float* smooth_w = (const float*)d_in[24];
  const float* smg = (const float*)d_in[25];
  const float* smb = (const float*)d_in[26];
  float* dout = (float*)d_out;

  char* wsb = (char*)d_ws;
  u16* cat = (u16*)wsb;                          // 25,165,824 B (CHWc bf16, 48 chunks)
  u16* Xt  = (u16*)(wsb + 25165824);             //  8,388,608 B (CHWc bf16, 16 chunks)
  u16* Wb  = (u16*)(wsb + 33554432);             // 14,155,776 B (packed frags)
  float* X  = (float*)(wsb + 47710208);          //  8,388,608 B (NCHW f32 conv out)
  float* Qt = (float*)(wsb + 56098816);          //  1,048,576 B
  float* sm = (float*)(wsb + 57147392);          // small pool
  float* Qs = sm;            // 64
  float* Ck = sm + 64;       // 32
  float* Mb = sm + 128;      // 16384
  float* Zb = Mb + 16384;    // 16384
  float* Graw = Zb + 16384;  // 16384
  float* G  = Graw + 16384;  // 16384
  float* EG = G + 16384;     // 32768
  float* ABf = EG + 32768;   // 16384
  float* stat = ABf + 16384; // 1024
  float2* AB = (float2*)ABf;

  // concat order: [x_8(c5), x_16(c4), x_32(c3)]
  run_branch<8>(c5, d_in + 17, cat, 0,    Xt, Wb, X, Qt, Qs, Ck, Mb, Zb, Graw, G, EG, AB, stream);
  run_branch<16>(c4, d_in + 10, cat, 512, Xt, Wb, X, Qt, Qs, Ck, Mb, Zb, Graw, G, EG, AB, stream);
  run_branch<32>(c3, d_in + 3, cat, 1024, Xt, Wb, X, Qt, Qs, Ck, Mb, Zb, Graw, G, EG, AB, stream);

  // smooth conv (cat CHWc bf16 -> dout NCHW f32), then BN2d + relu
  wpack_k<<<(512 * 1536) / 256, 256, 0, stream>>>(smooth_w, Wb, 1536, 512);
  convdir_k<1536, 512, 128, 64><<<512, 256, 0, stream>>>(cat, Wb, dout);
  bnstat_k<<<512, 256, 0, stream>>>(dout, stat);
  bnrelu_k<<<16384, 256, 0, stream>>>(dout, stat, smg, smb);
}

// Round 4
// 1078.978 us; speedup vs baseline: 5.6485x; 1.1697x over previous
//
#include <hip/hip_runtime.h>
#include <hip/hip_bf16.h>
#include <math.h>

#define HWN 4096      // 64*64
#define DCH 256
#define EPSV 1e-5f

typedef unsigned short u16;
typedef __attribute__((ext_vector_type(8))) short short8b;   // 8 bf16 payload
typedef __attribute__((ext_vector_type(4))) float fx4;
typedef __attribute__((ext_vector_type(8))) unsigned short u16x8;

static __device__ inline u16 f2bf(float f) {
  __hip_bfloat16 h = __float2bfloat16(f);
  return *reinterpret_cast<u16*>(&h);
}
static __device__ inline float bf2f(u16 u) {
  unsigned int v = ((unsigned int)u) << 16;
  return __uint_as_float(v);
}

// ---------------- NCHW f32 -> CHWc bf16 (chunks of 32 ci) ----------------
__global__ __launch_bounds__(256) void t_chwc_k(const float* __restrict__ in,
    u16* __restrict__ out, int C) {
  __shared__ float tl[32][257];
  const int p0 = blockIdx.x * 256, cic = blockIdx.y, b = blockIdx.z;
  const int t = threadIdx.x;
  const float* ip = in + ((size_t)(b * C + cic * 32)) * HWN + p0;
#pragma unroll
  for (int r = 0; r < 32; ++r) tl[r][t] = ip[(size_t)r * HWN + t];
  __syncthreads();
  u16* op = out + ((size_t)((b * (C / 32) + cic)) * HWN + p0 + t) * 32;
#pragma unroll
  for (int g = 0; g < 4; ++g) {
    u16x8 o;
#pragma unroll
    for (int j = 0; j < 8; ++j) o[j] = f2bf(tl[g * 8 + j][t]);
    *reinterpret_cast<u16x8*>(op + g * 8) = o;
  }
}

// ---------------- weights OIHW f32 -> fragment-packed bf16 ----------------
// packed[tap][cic][cog]: 1KB block, entry (kg*16+m)*8+j = w[cog*16+m][cic*32+kg*8+j][tap]
__global__ __launch_bounds__(256) void wpack_k(const float* __restrict__ w,
    u16* __restrict__ wp, int CIN, int COUT) {
  int idx = blockIdx.x * 256 + threadIdx.x;   // (co, ci)
  int co = idx / CIN, ci = idx % CIN;
  const float* src = w + (size_t)idx * 9;
  int cic = ci >> 5, kg = (ci >> 3) & 3, j = ci & 7;
  int cog = co >> 4, m = co & 15;
  size_t base = ((size_t)cic * (COUT / 16) + cog) * 512 + kg * 128 + m * 8 + j;
  size_t tapstride = (size_t)(CIN / 32) * (COUT / 16) * 512;
#pragma unroll
  for (int tap = 0; tap < 9; ++tap)
    wp[tap * tapstride + base] = f2bf(src[tap]);
}

// ---------------- split-K direct MFMA conv 3x3 pad 1 ----------------
// wave = 64px (one image row) x 64co; block = 4 waves = 4 rows.
// grid = 32 rowtiles * (COUT/64) * SPLIT. Slab output per split chunk.
template<int CIN, int COUT, int SPLIT, bool BF16OUT>
__global__ __launch_bounds__(256) void convsp_k(
    const u16* __restrict__ xt, const u16* __restrict__ wp,
    void* __restrict__ outv) {
  constexpr int NCIC = CIN / 32;
  constexpr int NCO = COUT / 64;
  constexpr int CICPS = NCIC / SPLIT;
  constexpr size_t OUTEL = (size_t)2 * COUT * HWN;

  int g = blockIdx.x;
  const int cpx = (int)gridDim.x >> 3;
  g = (g & 7) * cpx + (g >> 3);
  const int s = g / (32 * NCO);
  const int rem = g % (32 * NCO);
  const int rt = rem / NCO;
  const int cob = (rem % NCO) * 64;

  const int wv = threadIdx.x >> 6, lane = threadIdx.x & 63;
  const int row = rt * 4 + wv;
  const int b = row >> 6, h = row & 63;
  const int m = lane & 15, kg = lane >> 4;

  fx4 acc[4][4];
#pragma unroll
  for (int i = 0; i < 4; ++i)
#pragma unroll
    for (int jn = 0; jn < 4; ++jn) acc[i][jn] = (fx4){0.f, 0.f, 0.f, 0.f};

  const short8b zero8 = (short8b){0, 0, 0, 0, 0, 0, 0, 0};

#pragma unroll 1
  for (int cic = s * CICPS; cic < (s + 1) * CICPS; ++cic) {
    const u16* xbase = xt + ((size_t)(b * NCIC + cic)) * HWN * 32;
#pragma unroll
    for (int ty = 0; ty < 3; ++ty) {
      const int hh = h + ty - 1;                 // wave-uniform
      if ((unsigned)hh < 64u) {
        const u16* rowp = xbase + (size_t)hh * 2048 + kg * 8;
#pragma unroll
        for (int tx = 0; tx < 3; ++tx) {
          short8b a[4];
#pragma unroll
          for (int mt = 0; mt < 4; ++mt) {
            int wi = mt * 16 + m + tx - 1;
            bool ok = ((unsigned)wi < 64u);
            int wc = ok ? wi : 0;
            short8b v = *reinterpret_cast<const short8b*>(rowp + wc * 32);
            a[mt] = ok ? v : zero8;
          }
          const int tap = ty * 3 + tx;
          const u16* wt = wp + (((size_t)tap * NCIC + cic) * (COUT / 16)
                                + (cob >> 4)) * 512 + lane * 8;
          short8b bb[4];
#pragma unroll
          for (int nt = 0; nt < 4; ++nt)
            bb[nt] = *reinterpret_cast<const short8b*>(wt + nt * 512);
#pragma unroll
          for (int mt = 0; mt < 4; ++mt)
#pragma unroll
            for (int nt = 0; nt < 4; ++nt)
              acc[mt][nt] = __builtin_amdgcn_mfma_f32_16x16x32_bf16(a[mt], bb[nt], acc[mt][nt], 0, 0, 0);
        }
      }
    }
  }

  // epilogue: D col = co-in-16 = m, row = pixel = mt*16 + kg*4 + reg
#pragma unroll
  for (int mt = 0; mt < 4; ++mt)
#pragma unroll
    for (int nt = 0; nt < 4; ++nt) {
      int co = cob + nt * 16 + m;
      size_t idx = ((size_t)(b * COUT + co)) * HWN + h * 64 + mt * 16 + kg * 4;
      if (BF16OUT) {
        u16* op = (u16*)outv + s * OUTEL + idx;
        ushort4 o;
        o.x = f2bf(acc[mt][nt][0]); o.y = f2bf(acc[mt][nt][1]);
        o.z = f2bf(acc[mt][nt][2]); o.w = f2bf(acc[mt][nt][3]);
        *reinterpret_cast<ushort4*>(op) = o;
      } else {
        float* op = (float*)outv + s * OUTEL + idx;
        *reinterpret_cast<fx4*>(op) = acc[mt][nt];
      }
    }
}

// ---------------- slab reductions ----------------
__global__ __launch_bounds__(256) void breduce_k(const u16* __restrict__ slab,
    float* __restrict__ X) {   // 4 bf16 slabs of 2*256*4096
  const size_t i0 = ((size_t)blockIdx.x * 256 + threadIdx.x) * 8;
  const size_t el = (size_t)2 * DCH * HWN;
  u16x8 s0 = *reinterpret_cast<const u16x8*>(slab + i0);
  u16x8 s1 = *reinterpret_cast<const u16x8*>(slab + el + i0);
  u16x8 s2 = *reinterpret_cast<const u16x8*>(slab + 2 * el + i0);
  u16x8 s3 = *reinterpret_cast<const u16x8*>(slab + 3 * el + i0);
  fx4 o0, o1;
#pragma unroll
  for (int j = 0; j < 4; ++j)
    o0[j] = (bf2f(s0[j]) + bf2f(s1[j])) + (bf2f(s2[j]) + bf2f(s3[j]));
#pragma unroll
  for (int j = 0; j < 4; ++j)
    o1[j] = (bf2f(s0[4 + j]) + bf2f(s1[4 + j])) + (bf2f(s2[4 + j]) + bf2f(s3[4 + j]));
  *reinterpret_cast<fx4*>(X + i0) = o0;
  *reinterpret_cast<fx4*>(X + i0 + 4) = o1;
}

__global__ __launch_bounds__(256) void sreduce_k(const float* __restrict__ slab,
    float* __restrict__ dout) {  // 2 f32 slabs of 2*512*4096
  const size_t i0 = ((size_t)blockIdx.x * 256 + threadIdx.x) * 4;
  const size_t el = (size_t)2 * 512 * HWN;
  fx4 a = *reinterpret_cast<const fx4*>(slab + i0);
  fx4 bvec = *reinterpret_cast<const fx4*>(slab + el + i0);
#pragma unroll
  for (int j = 0; j < 4; ++j) a[j] += bvec[j];
  *reinterpret_cast<fx4*>(dout + i0) = a;
}

// ---------------- AB + Ck precompute (one launch) ----------------
template<int K>
__global__ __launch_bounds__(256) void prep_ck_k(const float* __restrict__ sc,
    const float* __restrict__ cw, float2* __restrict__ AB, float* __restrict__ Ck) {
  const int k = blockIdx.x, d = threadIdx.x;
  float s = sc[d * K + k];
  float a = s * s;
  float c = cw[k * DCH + d];
  AB[d * K + k] = make_float2(a, c * a);
  float t = c * s;
  t = t * t;
  __shared__ float red[4];
  for (int off = 32; off; off >>= 1) t += __shfl_down(t, off);
  int lane = threadIdx.x & 63, wid = threadIdx.x >> 6;
  if (lane == 0) red[wid] = t;
  __syncthreads();
  if (threadIdx.x == 0) Ck[k] = red[0] + red[1] + red[2] + red[3];
}

// ---------------- scores + softmax -> Qt[b][k][n] ----------------
template<int K>
__global__ __launch_bounds__(64) void score_k(const float* __restrict__ X,
    const float2* __restrict__ AB, const float* __restrict__ Ck,
    float* __restrict__ Qt) {
  const int b = blockIdx.y;
  const int n = blockIdx.x * 64 + threadIdx.x;
  const float* xp = X + ((size_t)b * DCH) * HWN + n;
  float s_[K];
#pragma unroll
  for (int k = 0; k < K; ++k) s_[k] = 0.f;
  for (int d = 0; d < DCH; ++d) {
    float xv = xp[(size_t)d * HWN];
    float x2 = xv * xv;
    float xm = -2.f * xv;
    const float2* abp = AB + d * K;
#pragma unroll
    for (int k = 0; k < K; ++k) {
      float2 ab = abp[k];
      s_[k] = fmaf(x2, ab.x, s_[k]);
      s_[k] = fmaf(xm, ab.y, s_[k]);
    }
  }
  float mx = -1e30f;
#pragma unroll
  for (int k = 0; k < K; ++k) { s_[k] = -0.5f * (s_[k] + Ck[k]); mx = fmaxf(mx, s_[k]); }
  float sum = 0.f;
#pragma unroll
  for (int k = 0; k < K; ++k) { float e = expf(s_[k] - mx); s_[k] = e; sum += e; }
  float inv = 1.f / sum;
#pragma unroll
  for (int k = 0; k < K; ++k) Qt[((size_t)(b * K + k)) * HWN + n] = s_[k] * inv;
}

// ---------------- Qs[b][k] = sum_n Qt ----------------
__global__ __launch_bounds__(256) void qsum_k(const float* __restrict__ Qt,
    float* __restrict__ Qs, int K) {
  int k = blockIdx.x, b = blockIdx.y;
  const float* qp = Qt + ((size_t)(b * K + k)) * HWN;
  float s = 0.f;
  for (int n = threadIdx.x; n < HWN; n += 256) s += qp[n];
  __shared__ float red[4];
  for (int off = 32; off; off >>= 1) s += __shfl_down(s, off);
  int lane = threadIdx.x & 63, wid = threadIdx.x >> 6;
  if (lane == 0) red[wid] = s;
  __syncthreads();
  if (threadIdx.x == 0) Qs[b * K + k] = red[0] + red[1] + red[2] + red[3];
}

// ---------------- M[b][d][k] = sum_n X[b][d][n] * Qt[b][k][n] ----------------
__global__ __launch_bounds__(256) void mmul_k(const float* __restrict__ X,
    const float* __restrict__ Qt, float* __restrict__ M, int K) {
  __shared__ float4 xr4[HWN / 4];
  __shared__ float red[4];
  float* xr = (float*)xr4;
  const int d = blockIdx.x, b = blockIdx.y;
  const float4* xp4 = (const float4*)(X + ((size_t)(b * DCH + d)) * HWN);
  for (int i = threadIdx.x; i < HWN / 4; i += 256) xr4[i] = xp4[i];
  __syncthreads();
  const int lane = threadIdx.x & 63, wid = threadIdx.x >> 6;
  for (int k = 0; k < K; ++k) {
    const float* qp = Qt + ((size_t)(b * K + k)) * HWN;
    float s = 0.f;
    for (int n = threadIdx.x; n < HWN; n += 256) s = fmaf(xr[n], qp[n], s);
    for (int off = 32; off; off >>= 1) s += __shfl_down(s, off);
    if (lane == 0) red[wid] = s;
    __syncthreads();
    if (threadIdx.x == 0) M[((size_t)(b * DCH + d)) * K + k] = red[0] + red[1] + red[2] + red[3];
    __syncthreads();
  }
}

// ---------------- fuse1: Z build + L2norm + graph adj/support/relu ----------------
template<int K>
__global__ __launch_bounds__(256) void fuse1_k(const float* __restrict__ M,
    const float* __restrict__ Qs, const float* __restrict__ sc,
    const float* __restrict__ cw, const float* __restrict__ Wm,
    float* __restrict__ Graw) {
  __shared__ float zl[DCH * K];
  __shared__ float adj[K * K];
  __shared__ float rn[K];
  const int b = blockIdx.x, t = threadIdx.x;
  // z
#pragma unroll
  for (int k = 0; k < K; ++k) {
    float qs = Qs[b * K + k];
    float mm = M[((size_t)(b * DCH + t)) * K + k];
    zl[t * K + k] = sc[t * K + k] * (mm - cw[k * DCH + t] * qs) / qs;
  }
  __syncthreads();
  if (t < K) {
    float s = 0.f;
    for (int i = 0; i < DCH; ++i) { float v = zl[i * K + t]; s = fmaf(v, v, s); }
    rn[t] = 1.f / sqrtf(s);
  }
  __syncthreads();
#pragma unroll
  for (int k = 0; k < K; ++k) zl[t * K + k] *= rn[k];
  __syncthreads();
  // adj
  for (int p = t; p < K * K; p += 256) {
    int k = p / K, l = p % K;
    float s = 0.f;
    for (int i = 0; i < DCH; ++i) s = fmaf(zl[i * K + k], zl[i * K + l], s);
    adj[p] = s;
  }
  __syncthreads();
  // support @ adj, relu
  float sup[K];
#pragma unroll
  for (int k = 0; k < K; ++k) sup[k] = 0.f;
  const float* wr = Wm + (size_t)t * DCH;
  for (int jj = 0; jj < DCH; ++jj) {
    float wv = wr[jj];
#pragma unroll
    for (int k = 0; k < K; ++k) sup[k] = fmaf(wv, zl[jj * K + k], sup[k]);
  }
#pragma unroll
  for (int l = 0; l < K; ++l) {
    float s = 0.f;
#pragma unroll
    for (int k = 0; k < K; ++k) s = fmaf(sup[k], adj[k * K + l], s);
    Graw[((size_t)(b * DCH + t)) * K + l] = fmaxf(s, 0.f);
  }
}

// ---------------- fuse2: BN1d (redundant per block) + EG ----------------
template<int K>
__global__ __launch_bounds__(256) void fuse2_k(const float* __restrict__ Graw,
    const float* __restrict__ gamma, const float* __restrict__ beta,
    const float* __restrict__ E, float* __restrict__ EG) {
  __shared__ float gl[DCH * K];
  const int b = blockIdx.x, t = threadIdx.x;
  // BN stats over both batches for channel t
  float s = 0.f, ss = 0.f;
#pragma unroll
  for (int b2 = 0; b2 < 2; ++b2)
#pragma unroll
    for (int l = 0; l < K; ++l) {
      float v = Graw[((size_t)(b2 * DCH + t)) * K + l];
      s += v; ss = fmaf(v, v, ss);
    }
  const float invn = 1.f / (2 * K);
  float mean = s * invn;
  float var  = ss * invn - mean * mean;
  float giv  = gamma[t] / sqrtf(var + EPSV);
  float be   = beta[t];
#pragma unroll
  for (int l = 0; l < K; ++l) {
    float v = Graw[((size_t)(b * DCH + t)) * K + l];
    gl[t * K + l] = fmaf(v - mean, giv, be);
  }
  __syncthreads();
  float a1[K], a2[K];
#pragma unroll
  for (int k = 0; k < K; ++k) { a1[k] = 0.f; a2[k] = 0.f; }
  const float* e1 = E + (size_t)t * DCH;
  const float* e2 = E + (size_t)(t + 256) * DCH;
  for (int d = 0; d < DCH; ++d) {
    float v1 = e1[d], v2 = e2[d];
#pragma unroll
    for (int k = 0; k < K; ++k) {
      a1[k] = fmaf(v1, gl[d * K + k], a1[k]);
      a2[k] = fmaf(v2, gl[d * K + k], a2[k]);
    }
  }
#pragma unroll
  for (int k = 0; k < K; ++k) {
    EG[((size_t)(b * 512 + t)) * K + k] = a1[k];
    EG[((size_t)(b * 512 + t + 256)) * K + k] = a2[k];
  }
}

// ---------------- Y = EG @ Qt + c -> CHWc bf16 cat ----------------
template<int K>
__global__ __launch_bounds__(256) void yout_chwc_k(const float* __restrict__ EG,
    const float* __restrict__ Qt, const float* __restrict__ cres,
    u16* __restrict__ cat, int coff) {
  __shared__ u16 egl[K * 512];
  const int b = blockIdx.y;
  const int t = threadIdx.x;
  const int n = blockIdx.x * 64 + (t & 63);
  const int cog = t >> 6;
  for (int i = t; i < K * 512; i += 256) {
    int k = i / 512, co = i % 512;
    egl[i] = f2bf(EG[((size_t)(b * 512 + co)) * K + k]);
  }
  float q[K];
#pragma unroll
  for (int k = 0; k < K; ++k) q[k] = Qt[((size_t)(b * K + k)) * HWN + n];
  __syncthreads();
  const float* crow = cres + (size_t)b * 512 * HWN + n;
#pragma unroll 1
  for (int it = 0; it < 16; ++it) {
    int co = cog * 128 + it * 8;
    float y[8];
#pragma unroll
    for (int jj = 0; jj < 8; ++jj) y[jj] = crow[(size_t)(co + jj) * HWN];
#pragma unroll
    for (int k = 0; k < K; ++k) {
      u16x8 eg = *reinterpret_cast<const u16x8*>(&egl[k * 512 + co]);
#pragma unroll
      for (int jj = 0; jj < 8; ++jj) y[jj] = fmaf(bf2f(eg[jj]), q[k], y[jj]);
    }
    u16x8 o;
#pragma unroll
    for (int jj = 0; jj < 8; ++jj) o[jj] = f2bf(y[jj]);
    int ch = coff + co;
    *reinterpret_cast<u16x8*>(cat +
        (((size_t)(b * 48 + (ch >> 5)) * HWN + n) * 32 + (co & 31))) = o;
  }
}

// ---------------- smooth BN stats + relu ----------------
__global__ __launch_bounds__(256) void bnstat_k(const float* __restrict__ out,
    float* __restrict__ stat) {
  const int o = blockIdx.x;
  float s = 0.f, ss = 0.f;
  for (int i = threadIdx.x; i < 2 * HWN; i += 256) {
    int b = i >> 12, n = i & (HWN - 1);
    float v = out[((size_t)(b * 512 + o)) * HWN + n];
    s += v; ss = fmaf(v, v, ss);
  }
  __shared__ float rs[4], rss[4];
  for (int off = 32; off; off >>= 1) { s += __shfl_down(s, off); ss += __shfl_down(ss, off); }
  int lane = threadIdx.x & 63, wid = threadIdx.x >> 6;
  if (lane == 0) { rs[wid] = s; rss[wid] = ss; }
  __syncthreads();
  if (threadIdx.x == 0) {
    float S = rs[0] + rs[1] + rs[2] + rs[3];
    float SS = rss[0] + rss[1] + rss[2] + rss[3];
    float mean = S / (2 * HWN);
    float var  = SS / (2 * HWN) - mean * mean;
    stat[o] = mean;
    stat[512 + o] = 1.f / sqrtf(var + EPSV);
  }
}

__global__ __launch_bounds__(256) void bnrelu_k(float* __restrict__ out,
    const float* __restrict__ stat, const float* __restrict__ g,
    const float* __restrict__ bb) {
  int idx = blockIdx.x * 256 + threadIdx.x;
  int o = (idx >> 12) & 511;
  float v = out[idx];
  float r = fmaf((v - stat[o]) * stat[512 + o], g[o], bb[o]);
  out[idx] = fmaxf(r, 0.f);
}

// ---------------- branch driver ----------------
template<int K>
static void run_branch(const float* cin, void* const* din, u16* cat, int coff,
                       u16* Xt, u16* Wb, u16* bslab, float* X, float* Qt,
                       float* Qs, float* Ck, float* Mb, float* Graw,
                       float* EG, float2* AB, hipStream_t stream) {
  const float* convw = (const float*)din[0];
  const float* cw    = (const float*)din[1];
  const float* sc    = (const float*)din[2];
  const float* gcnw  = (const float*)din[3];
  const float* bng   = (const float*)din[4];
  const float* bnb   = (const float*)din[5];
  const float* extw  = (const float*)din[6];
  t_chwc_k<<<dim3(16, 16, 2), 256, 0, stream>>>(cin, Xt, 512);
  wpack_k<<<(256 * 512) / 256, 256, 0, stream>>>(convw, Wb, 512, 256);
  convsp_k<512, 256, 4, true><<<512, 256, 0, stream>>>(Xt, Wb, bslab);
  breduce_k<<<1024, 256, 0, stream>>>(bslab, X);
  prep_ck_k<K><<<K, 256, 0, stream>>>(sc, cw, AB, Ck);
  score_k<K><<<dim3(64, 2), 64, 0, stream>>>(X, AB, Ck, Qt);
  qsum_k<<<dim3(K, 2), 256, 0, stream>>>(Qt, Qs, K);
  mmul_k<<<dim3(256, 2), 256, 0, stream>>>(X, Qt, Mb, K);
  fuse1_k<K><<<2, 256, 0, stream>>>(Mb, Qs, sc, cw, gcnw, Graw);
  fuse2_k<K><<<2, 256, 0, stream>>>(Graw, bng, bnb, extw, EG);
  yout_chwc_k<K><<<dim3(64, 2), 256, 0, stream>>>(EG, Qt, cin, cat, coff);
}

extern "C" void kernel_launch(void* const* d_in, const int* in_sizes, int n_in,
                              void* d_out, int out_size, void* d_ws, size_t ws_size,
                              hipStream_t stream) {
  const float* c3 = (const float*)d_in[0];
  const float* c4 = (const float*)d_in[1];
  const float* c5 = (const float*)d_in[2];
  const float* smooth_w = (const float*)d_in[24];
  const float* smg = (const float*)d_in[25];
  const float* smb = (const float*)d_in[26];
  float* dout = (float*)d_out;

  char* wsb = (char*)d_ws;
  u16* cat   = (u16*)wsb;                        // 25,165,824 B
  u16* Wb    = (u16*)(wsb + 25165824);           // 14,155,776 B (max, smooth)
  float* Qt  = (float*)(wsb + 39321600);         //  1,048,576 B
  float* sm  = (float*)(wsb + 40370176);         //    524,288 B small pool
  float* Qs  = sm;            // 64
  float* Ck  = sm + 64;       // 32
  float* Mb  = sm + 128;      // 16384
  float* Graw = Mb + 16384;   // 16384
  float* EG  = Graw + 16384;  // 32768
  float* ABf = EG + 32768;    // 16384
  float* stat = ABf + 16384;  // 1024
  float2* AB = (float2*)ABf;
  // region R @ 40,894,464: branch {Xt 8.4M | X 8.4M | bslab 16.8M} / smooth {sslab 33.6M}
  char* R = wsb + 40894464;
  u16* Xt      = (u16*)R;
  float* X     = (float*)(R + 8388608);
  u16* bslab   = (u16*)(R + 16777216);
  float* sslab = (float*)R;

  // concat order: [x_8(c5), x_16(c4), x_32(c3)]
  run_branch<8>(c5, d_in + 17, cat, 0,    Xt, Wb, bslab, X, Qt, Qs, Ck, Mb, Graw, EG, AB, stream);
  run_branch<16>(c4, d_in + 10, cat, 512, Xt, Wb, bslab, X, Qt, Qs, Ck, Mb, Graw, EG, AB, stream);
  run_branch<32>(c3, d_in + 3, cat, 1024, Xt, Wb, bslab, X, Qt, Qs, Ck, Mb, Graw, EG, AB, stream);

  // smooth conv (cat CHWc bf16 -> slabs f32 -> dout), then BN2d + relu
  wpack_k<<<(512 * 1536) / 256, 256, 0, stream>>>(smooth_w, Wb, 1536, 512);
  convsp_k<1536, 512, 2, false><<<512, 256, 0, stream>>>(cat, Wb, sslab);
  sreduce_k<<<4096, 256, 0, stream>>>(sslab, dout);
  bnstat_k<<<512, 256, 0, stream>>>(dout, stat);
  bnrelu_k<<<16384, 256, 0, stream>>>(dout, stat, smg, smb);
}

// Round 5
// 713.991 us; speedup vs baseline: 8.5360x; 1.5112x over previous
//
#include <hip/hip_runtime.h>
#include <hip/hip_bf16.h>
#include <math.h>

#define HWN 4096      // 64*64
#define DCH 256
#define EPSV 1e-5f

typedef unsigned short u16;
typedef __attribute__((ext_vector_type(8))) short short8b;   // 8 bf16 payload
typedef __attribute__((ext_vector_type(4))) float fx4;
typedef __attribute__((ext_vector_type(8))) unsigned short u16x8;

static __device__ inline u16 f2bf(float f) {
  __hip_bfloat16 h = __float2bfloat16(f);
  return *reinterpret_cast<u16*>(&h);
}
static __device__ inline float bf2f(u16 u) {
  unsigned int v = ((unsigned int)u) << 16;
  return __uint_as_float(v);
}

// ---------------- batched NCHW f32 -> CHWc bf16 (3 branches x 2 batch) ----------------
// Xt3 layout: [br][b][cic(16)][pix][32]
__global__ __launch_bounds__(256) void t_chwc3_k(const float* __restrict__ i0p,
    const float* __restrict__ i1p, const float* __restrict__ i2p,
    u16* __restrict__ out) {
  __shared__ float tl[32][257];
  const int p0 = blockIdx.x * 256, cic = blockIdx.y;
  const int z = blockIdx.z;             // br*2 + b
  const int br = z >> 1, b = z & 1;
  const float* in = (br == 0) ? i0p : ((br == 1) ? i1p : i2p);
  const int t = threadIdx.x;
  const float* ip = in + ((size_t)(b * 512 + cic * 32)) * HWN + p0;
#pragma unroll
  for (int r = 0; r < 32; ++r) tl[r][t] = ip[(size_t)r * HWN + t];
  __syncthreads();
  u16* op = out + ((size_t)((z * 16 + cic)) * HWN + p0 + t) * 32;
#pragma unroll
  for (int g = 0; g < 4; ++g) {
    u16x8 o;
#pragma unroll
    for (int j = 0; j < 8; ++j) o[j] = f2bf(tl[g * 8 + j][t]);
    *reinterpret_cast<u16x8*>(op + g * 8) = o;
  }
}

// ---------------- weights OIHW f32 -> fragment-packed bf16 (coalesced, LDS-staged) ----
// packed[br][tap][cic][cog]: 1KB block; entry e=(kg*16+m)*8+j = w[cog*16+m][cic*32+kg*8+j][tap]
template<int CIN, int COUT>
__global__ __launch_bounds__(256) void wpack_k(const float* __restrict__ w0,
    const float* __restrict__ w1, const float* __restrict__ w2,
    u16* __restrict__ wp) {
  constexpr int NCIC = CIN / 32, NCOG = COUT / 16;
  const int br = blockIdx.y;
  const float* w = (br == 0) ? w0 : ((br == 1) ? w1 : w2);
  u16* wpb = wp + (size_t)br * 9 * NCIC * NCOG * 512;
  const int cog = blockIdx.x % NCOG, cic = blockIdx.x / NCOG;
  __shared__ float ws_[16 * 32 * 9];    // 18 KB
  const int t = threadIdx.x;
  const float* src = w + ((size_t)(cog * 16) * CIN + cic * 32) * 9;
  for (int i = t; i < 4608; i += 256) {
    int co = i / 288, r = i % 288;
    ws_[i] = src[(size_t)co * CIN * 9 + r];
  }
  __syncthreads();
  const size_t tapstride = (size_t)NCIC * NCOG * 512;
  const size_t base = ((size_t)cic * NCOG + cog) * 512;
#pragma unroll
  for (int tap = 0; tap < 9; ++tap) {
#pragma unroll
    for (int e0 = 0; e0 < 512; e0 += 256) {
      int e = e0 + t;
      int kg = e >> 7, m = (e >> 3) & 15, j = e & 7;
      wpb[tap * tapstride + base + e] = f2bf(ws_[m * 288 + (kg * 8 + j) * 9 + tap]);
    }
  }
}

// ---------------- split-K direct MFMA conv 3x3 pad 1 (branch-batched via grid.y) ------
// wave = 64px (one image row) x 64co; block = 4 waves. grid.x = 32*NCO*SPLIT, grid.y = #br
template<int CIN, int COUT, int SPLIT, bool BF16OUT>
__global__ __launch_bounds__(256) void convsp_k(
    const u16* __restrict__ xt, const u16* __restrict__ wp,
    void* __restrict__ outv) {
  constexpr int NCIC = CIN / 32;
  constexpr int NCO = COUT / 64;
  constexpr int CICPS = NCIC / SPLIT;
  constexpr size_t OUTEL = (size_t)2 * COUT * HWN;
  const int br = blockIdx.y;
  xt += (size_t)br * 2 * NCIC * HWN * 32;
  wp += (size_t)br * 9 * NCIC * (COUT / 16) * 512;

  int g = blockIdx.x;
  const int cpx = (int)gridDim.x >> 3;
  g = (g & 7) * cpx + (g >> 3);
  const int s = g / (32 * NCO);
  const int rem = g % (32 * NCO);
  const int rt = rem / NCO;
  const int cob = (rem % NCO) * 64;

  const int wv = threadIdx.x >> 6, lane = threadIdx.x & 63;
  const int row = rt * 4 + wv;
  const int b = row >> 6, h = row & 63;
  const int m = lane & 15, kg = lane >> 4;

  fx4 acc[4][4];
#pragma unroll
  for (int i = 0; i < 4; ++i)
#pragma unroll
    for (int jn = 0; jn < 4; ++jn) acc[i][jn] = (fx4){0.f, 0.f, 0.f, 0.f};

  const short8b zero8 = (short8b){0, 0, 0, 0, 0, 0, 0, 0};

#pragma unroll 1
  for (int cic = s * CICPS; cic < (s + 1) * CICPS; ++cic) {
    const u16* xbase = xt + ((size_t)(b * NCIC + cic)) * HWN * 32;
#pragma unroll
    for (int ty = 0; ty < 3; ++ty) {
      const int hh = h + ty - 1;                 // wave-uniform
      if ((unsigned)hh < 64u) {
        const u16* rowp = xbase + (size_t)hh * 2048 + kg * 8;
#pragma unroll
        for (int tx = 0; tx < 3; ++tx) {
          short8b a[4];
#pragma unroll
          for (int mt = 0; mt < 4; ++mt) {
            int wi = mt * 16 + m + tx - 1;
            bool ok = ((unsigned)wi < 64u);
            int wc = ok ? wi : 0;
            short8b v = *reinterpret_cast<const short8b*>(rowp + wc * 32);
            a[mt] = ok ? v : zero8;
          }
          const int tap = ty * 3 + tx;
          const u16* wt = wp + (((size_t)tap * NCIC + cic) * (COUT / 16)
                                + (cob >> 4)) * 512 + lane * 8;
          short8b bb[4];
#pragma unroll
          for (int nt = 0; nt < 4; ++nt)
            bb[nt] = *reinterpret_cast<const short8b*>(wt + nt * 512);
#pragma unroll
          for (int mt = 0; mt < 4; ++mt)
#pragma unroll
            for (int nt = 0; nt < 4; ++nt)
              acc[mt][nt] = __builtin_amdgcn_mfma_f32_16x16x32_bf16(a[mt], bb[nt], acc[mt][nt], 0, 0, 0);
        }
      }
    }
  }

#pragma unroll
  for (int mt = 0; mt < 4; ++mt)
#pragma unroll
    for (int nt = 0; nt < 4; ++nt) {
      int co = cob + nt * 16 + m;
      size_t idx = ((size_t)(b * COUT + co)) * HWN + h * 64 + mt * 16 + kg * 4;
      if (BF16OUT) {
        u16* op = (u16*)outv + (size_t)(br * SPLIT + s) * OUTEL + idx;
        ushort4 o;
        o.x = f2bf(acc[mt][nt][0]); o.y = f2bf(acc[mt][nt][1]);
        o.z = f2bf(acc[mt][nt][2]); o.w = f2bf(acc[mt][nt][3]);
        *reinterpret_cast<ushort4*>(op) = o;
      } else {
        float* op = (float*)outv + (size_t)(br * SPLIT + s) * OUTEL + idx;
        *reinterpret_cast<fx4*>(op) = acc[mt][nt];
      }
    }
}

// ---------------- slab reductions ----------------
__global__ __launch_bounds__(256) void breduce_k(const u16* __restrict__ slab,
    float* __restrict__ X) {   // per branch: 4 bf16 slabs of 2*256*4096
  const int br = blockIdx.x >> 10;
  const size_t el = (size_t)2 * DCH * HWN;
  const u16* sb = slab + (size_t)br * 4 * el;
  float* Xb = X + (size_t)br * el;
  const size_t i0 = ((size_t)(blockIdx.x & 1023) * 256 + threadIdx.x) * 8;
  u16x8 s0 = *reinterpret_cast<const u16x8*>(sb + i0);
  u16x8 s1 = *reinterpret_cast<const u16x8*>(sb + el + i0);
  u16x8 s2 = *reinterpret_cast<const u16x8*>(sb + 2 * el + i0);
  u16x8 s3 = *reinterpret_cast<const u16x8*>(sb + 3 * el + i0);
  fx4 o0, o1;
#pragma unroll
  for (int j = 0; j < 4; ++j)
    o0[j] = (bf2f(s0[j]) + bf2f(s1[j])) + (bf2f(s2[j]) + bf2f(s3[j]));
#pragma unroll
  for (int j = 0; j < 4; ++j)
    o1[j] = (bf2f(s0[4 + j]) + bf2f(s1[4 + j])) + (bf2f(s2[4 + j]) + bf2f(s3[4 + j]));
  *reinterpret_cast<fx4*>(Xb + i0) = o0;
  *reinterpret_cast<fx4*>(Xb + i0 + 4) = o1;
}

__global__ __launch_bounds__(256) void sreduce_k(const float* __restrict__ slab,
    float* __restrict__ dout) {  // 3 f32 slabs of 2*512*4096
  const size_t i0 = ((size_t)blockIdx.x * 256 + threadIdx.x) * 4;
  const size_t el = (size_t)2 * 512 * HWN;
  fx4 a = *reinterpret_cast<const fx4*>(slab + i0);
  fx4 bvec = *reinterpret_cast<const fx4*>(slab + el + i0);
  fx4 cvec = *reinterpret_cast<const fx4*>(slab + 2 * el + i0);
#pragma unroll
  for (int j = 0; j < 4; ++j) a[j] = (a[j] + bvec[j]) + cvec[j];
  *reinterpret_cast<fx4*>(dout + i0) = a;
}

// ---------------- AB + Ck precompute ----------------
template<int K>
__global__ __launch_bounds__(256) void prep_ck_k(const float* __restrict__ sc,
    const float* __restrict__ cw, float2* __restrict__ AB, float* __restrict__ Ck) {
  const int k = blockIdx.x, d = threadIdx.x;
  float s = sc[d * K + k];
  float a = s * s;
  float c = cw[k * DCH + d];
  AB[d * K + k] = make_float2(a, c * a);
  float t = c * s;
  t = t * t;
  __shared__ float red[4];
  for (int off = 32; off; off >>= 1) t += __shfl_down(t, off);
  int lane = threadIdx.x & 63, wid = threadIdx.x >> 6;
  if (lane == 0) red[wid] = t;
  __syncthreads();
  if (threadIdx.x == 0) Ck[k] = red[0] + red[1] + red[2] + red[3];
}

// ---------------- scores + softmax -> Qt[b][k][n] (4 d-groups per block) -------------
template<int K>
__global__ __launch_bounds__(256) void score_k(const float* __restrict__ X,
    const float2* __restrict__ AB, const float* __restrict__ Ck,
    float* __restrict__ Qt) {
  __shared__ float sm[4 * 64 * (K + 1)];
  const int b = blockIdx.y;
  const int lane = threadIdx.x & 63;
  const int g = threadIdx.x >> 6;
  const int n = blockIdx.x * 64 + lane;
  const float* xp = X + ((size_t)b * DCH) * HWN + n;
  float s_[K];
#pragma unroll
  for (int k = 0; k < K; ++k) s_[k] = 0.f;
  for (int d = g * 64; d < g * 64 + 64; ++d) {
    float xv = xp[(size_t)d * HWN];
    float x2 = xv * xv;
    float xm = -2.f * xv;
    const float2* abp = AB + d * K;
#pragma unroll
    for (int k = 0; k < K; ++k) {
      float2 ab = abp[k];
      s_[k] = fmaf(x2, ab.x, s_[k]);
      s_[k] = fmaf(xm, ab.y, s_[k]);
    }
  }
  float* smr = sm + (g * 64 + lane) * (K + 1);
#pragma unroll
  for (int k = 0; k < K; ++k) smr[k] = s_[k];
  __syncthreads();
  if (g == 0) {
    const float* r0 = sm + lane * (K + 1);
    const float* r1 = sm + (64 + lane) * (K + 1);
    const float* r2 = sm + (128 + lane) * (K + 1);
    const float* r3 = sm + (192 + lane) * (K + 1);
    float mx = -1e30f;
#pragma unroll
    for (int k = 0; k < K; ++k) {
      float v = (r0[k] + r1[k]) + (r2[k] + r3[k]);
      s_[k] = -0.5f * (v + Ck[k]);
      mx = fmaxf(mx, s_[k]);
    }
    float sum = 0.f;
#pragma unroll
    for (int k = 0; k < K; ++k) { float e = expf(s_[k] - mx); s_[k] = e; sum += e; }
    float inv = 1.f / sum;
#pragma unroll
    for (int k = 0; k < K; ++k) Qt[((size_t)(b * K + k)) * HWN + n] = s_[k] * inv;
  }
}

// ---------------- Qs[b][k] = sum_n Qt ----------------
__global__ __launch_bounds__(256) void qsum_k(const float* __restrict__ Qt,
    float* __restrict__ Qs, int K) {
  int k = blockIdx.x, b = blockIdx.y;
  const float* qp = Qt + ((size_t)(b * K + k)) * HWN;
  float s = 0.f;
  for (int n = threadIdx.x; n < HWN; n += 256) s += qp[n];
  __shared__ float red[4];
  for (int off = 32; off; off >>= 1) s += __shfl_down(s, off);
  int lane = threadIdx.x & 63, wid = threadIdx.x >> 6;
  if (lane == 0) red[wid] = s;
  __syncthreads();
  if (threadIdx.x == 0) Qs[b * K + k] = red[0] + red[1] + red[2] + red[3];
}

// ---------------- Mp[b][d][k][nch] partials over 512-n chunks ----------------
template<int K>
__global__ __launch_bounds__(256) void mmulp_k(const float* __restrict__ X,
    const float* __restrict__ Qt, float* __restrict__ Mp) {
  __shared__ float xs[512];
  __shared__ float pw[4][K + 1];
  const int d = blockIdx.x, nch = blockIdx.y, b = blockIdx.z;
  const int t = threadIdx.x;
  const float* xp = X + ((size_t)(b * DCH + d)) * HWN + nch * 512;
  xs[t] = xp[t]; xs[t + 256] = xp[t + 256];
  __syncthreads();
  const int lane = t & 63, wid = t >> 6;
#pragma unroll
  for (int k = 0; k < K; ++k) {
    const float* qp = Qt + ((size_t)(b * K + k)) * HWN + nch * 512;
    float s = fmaf(xs[t], qp[t], xs[t + 256] * qp[t + 256]);
    for (int off = 32; off; off >>= 1) s += __shfl_down(s, off);
    if (lane == 0) pw[wid][k] = s;
  }
  __syncthreads();
  if (t < K)
    Mp[(((size_t)(b * DCH + d)) * K + t) * 8 + nch] =
        (pw[0][t] + pw[1][t]) + (pw[2][t] + pw[3][t]);
}

__global__ __launch_bounds__(256) void mred_k(const float* __restrict__ Mp,
    float* __restrict__ M, int total) {
  int i = blockIdx.x * 256 + threadIdx.x;
  if (i < total) {
    const float* p = Mp + (size_t)i * 8;
    M[i] = ((p[0] + p[1]) + (p[2] + p[3])) + ((p[4] + p[5]) + (p[6] + p[7]));
  }
}

// ---------------- fuse1: Z build + L2norm + graph adj/support/relu ----------------
template<int K>
__global__ __launch_bounds__(256) void fuse1_k(const float* __restrict__ M,
    const float* __restrict__ Qs, const float* __restrict__ sc,
    const float* __restrict__ cw, const float* __restrict__ Wm,
    float* __restrict__ Graw) {
  __shared__ float zl[DCH * K];
  __shared__ float adj[K * K];
  __shared__ float rn[K];
  const int b = blockIdx.x, t = threadIdx.x;
#pragma unroll
  for (int k = 0; k < K; ++k) {
    float qs = Qs[b * K + k];
    float mm = M[((size_t)(b * DCH + t)) * K + k];
    zl[t * K + k] = sc[t * K + k] * (mm - cw[k * DCH + t] * qs) / qs;
  }
  __syncthreads();
  if (t < K) {
    float s = 0.f;
    for (int i = 0; i < DCH; ++i) { float v = zl[i * K + t]; s = fmaf(v, v, s); }
    rn[t] = 1.f / sqrtf(s);
  }
  __syncthreads();
#pragma unroll
  for (int k = 0; k < K; ++k) zl[t * K + k] *= rn[k];
  __syncthreads();
  for (int p = t; p < K * K; p += 256) {
    int k = p / K, l = p % K;
    float s = 0.f;
    for (int i = 0; i < DCH; ++i) s = fmaf(zl[i * K + k], zl[i * K + l], s);
    adj[p] = s;
  }
  __syncthreads();
  float sup[K];
#pragma unroll
  for (int k = 0; k < K; ++k) sup[k] = 0.f;
  const float* wr = Wm + (size_t)t * DCH;
  for (int jj = 0; jj < DCH; ++jj) {
    float wv = wr[jj];
#pragma unroll
    for (int k = 0; k < K; ++k) sup[k] = fmaf(wv, zl[jj * K + k], sup[k]);
  }
#pragma unroll
  for (int l = 0; l < K; ++l) {
    float s = 0.f;
#pragma unroll
    for (int k = 0; k < K; ++k) s = fmaf(sup[k], adj[k * K + l], s);
    Graw[((size_t)(b * DCH + t)) * K + l] = fmaxf(s, 0.f);
  }
}

// ---------------- fuse2: BN1d (redundant per block) + EG (split over 8 blocks) --------
template<int K>
__global__ __launch_bounds__(256) void fuse2_k(const float* __restrict__ Graw,
    const float* __restrict__ gamma, const float* __restrict__ beta,
    const float* __restrict__ E, float* __restrict__ EG) {
  __shared__ float gl[DCH * K];
  __shared__ float er[128 * 2 * (K + 1)];
  const int b = blockIdx.x, ob = blockIdx.y, t = threadIdx.x;
  {
    const int d = t;
    float s = 0.f, ss = 0.f;
#pragma unroll
    for (int b2 = 0; b2 < 2; ++b2)
#pragma unroll
      for (int l = 0; l < K; ++l) {
        float v = Graw[((size_t)(b2 * DCH + d)) * K + l];
        s += v; ss = fmaf(v, v, ss);
      }
    const float invn = 1.f / (2 * K);
    float mean = s * invn;
    float var  = ss * invn - mean * mean;
    float giv  = gamma[d] / sqrtf(var + EPSV);
    float be   = beta[d];
#pragma unroll
    for (int l = 0; l < K; ++l) {
      float v = Graw[((size_t)(b * DCH + d)) * K + l];
      gl[d * K + l] = fmaf(v - mean, giv, be);
    }
  }
  __syncthreads();
  const int o = ob * 128 + (t >> 1);
  const int half = t & 1;
  float a[K];
#pragma unroll
  for (int k = 0; k < K; ++k) a[k] = 0.f;
  const float* e = E + (size_t)o * DCH + half * 128;
  for (int d = 0; d < 128; ++d) {
    float v = e[d];
#pragma unroll
    for (int k = 0; k < K; ++k) a[k] = fmaf(v, gl[(half * 128 + d) * K + k], a[k]);
  }
  float* erow = er + (size_t)(t >> 1) * (2 * (K + 1)) + half * (K + 1);
#pragma unroll
  for (int k = 0; k < K; ++k) erow[k] = a[k];
  __syncthreads();
  if (half == 0) {
    const float* e2 = er + (size_t)(t >> 1) * (2 * (K + 1));
#pragma unroll
    for (int k = 0; k < K; ++k)
      EG[((size_t)(b * 512 + o)) * K + k] = e2[k] + e2[K + 1 + k];
  }
}

// ---------------- Y = EG @ Qt + c -> CHWc bf16 cat ----------------
template<int K>
__global__ __launch_bounds__(256) void yout_chwc_k(const float* __restrict__ EG,
    const float* __restrict__ Qt, const float* __restrict__ cres,
    u16* __restrict__ cat, int coff) {
  __shared__ u16 egl[K * 512];
  const int b = blockIdx.y;
  const int t = threadIdx.x;
  const int n = blockIdx.x * 64 + (t & 63);
  const int cog = t >> 6;
  for (int i = t; i < K * 512; i += 256) {
    int k = i / 512, co = i % 512;
    egl[i] = f2bf(EG[((size_t)(b * 512 + co)) * K + k]);
  }
  float q[K];
#pragma unroll
  for (int k = 0; k < K; ++k) q[k] = Qt[((size_t)(b * K + k)) * HWN + n];
  __syncthreads();
  const float* crow = cres + (size_t)b * 512 * HWN + n;
#pragma unroll 1
  for (int it = 0; it < 16; ++it) {
    int co = cog * 128 + it * 8;
    float y[8];
#pragma unroll
    for (int jj = 0; jj < 8; ++jj) y[jj] = crow[(size_t)(co + jj) * HWN];
#pragma unroll
    for (int k = 0; k < K; ++k) {
      u16x8 eg = *reinterpret_cast<const u16x8*>(&egl[k * 512 + co]);
#pragma unroll
      for (int jj = 0; jj < 8; ++jj) y[jj] = fmaf(bf2f(eg[jj]), q[k], y[jj]);
    }
    u16x8 o;
#pragma unroll
    for (int jj = 0; jj < 8; ++jj) o[jj] = f2bf(y[jj]);
    int ch = coff + co;
    *reinterpret_cast<u16x8*>(cat +
        (((size_t)(b * 48 + (ch >> 5)) * HWN + n) * 32 + (co & 31))) = o;
  }
}

// ---------------- smooth BN stats + relu ----------------
__global__ __launch_bounds__(256) void bnstat_k(const float* __restrict__ out,
    float* __restrict__ stat) {
  const int o = blockIdx.x;
  float s = 0.f, ss = 0.f;
  for (int i = threadIdx.x; i < 2 * HWN; i += 256) {
    int b = i >> 12, n = i & (HWN - 1);
    float v = out[((size_t)(b * 512 + o)) * HWN + n];
    s += v; ss = fmaf(v, v, ss);
  }
  __shared__ float rs[4], rss[4];
  for (int off = 32; off; off >>= 1) { s += __shfl_down(s, off); ss += __shfl_down(ss, off); }
  int lane = threadIdx.x & 63, wid = threadIdx.x >> 6;
  if (lane == 0) { rs[wid] = s; rss[wid] = ss; }
  __syncthreads();
  if (threadIdx.x == 0) {
    float S = rs[0] + rs[1] + rs[2] + rs[3];
    float SS = rss[0] + rss[1] + rss[2] + rss[3];
    float mean = S / (2 * HWN);
    float var  = SS / (2 * HWN) - mean * mean;
    stat[o] = mean;
    stat[512 + o] = 1.f / sqrtf(var + EPSV);
  }
}

__global__ __launch_bounds__(256) void bnrelu_k(float* __restrict__ out,
    const float* __restrict__ stat, const float* __restrict__ g,
    const float* __restrict__ bb) {
  int idx = blockIdx.x * 256 + threadIdx.x;
  int o = (idx >> 12) & 511;
  float v = out[idx];
  float r = fmaf((v - stat[o]) * stat[512 + o], g[o], bb[o]);
  out[idx] = fmaxf(r, 0.f);
}

// ---------------- branch tail driver ----------------
template<int K>
static void run_tail(const float* cin, void* const* din, u16* cat, int coff,
                     const float* Xb, float* Qt, float* Qs, float* Ck,
                     float* Mb, float* Mp, float* Graw, float* EG, float2* AB,
                     hipStream_t stream) {
  const float* cw    = (const float*)din[1];
  const float* sc    = (const float*)din[2];
  const float* gcnw  = (const float*)din[3];
  const float* bng   = (const float*)din[4];
  const float* bnb   = (const float*)din[5];
  const float* extw  = (const float*)din[6];
  prep_ck_k<K><<<K, 256, 0, stream>>>(sc, cw, AB, Ck);
  score_k<K><<<dim3(64, 2), 256, 0, stream>>>(Xb, AB, Ck, Qt);
  qsum_k<<<dim3(K, 2), 256, 0, stream>>>(Qt, Qs, K);
  mmulp_k<K><<<dim3(256, 8, 2), 256, 0, stream>>>(Xb, Qt, Mp);
  mred_k<<<(2 * DCH * K + 255) / 256, 256, 0, stream>>>(Mp, Mb, 2 * DCH * K);
  fuse1_k<K><<<2, 256, 0, stream>>>(Mb, Qs, sc, cw, gcnw, Graw);
  fuse2_k<K><<<dim3(2, 4), 256, 0, stream>>>(Graw, bng, bnb, extw, EG);
  yout_chwc_k<K><<<dim3(64, 2), 256, 0, stream>>>(EG, Qt, cin, cat, coff);
}

extern "C" void kernel_launch(void* const* d_in, const int* in_sizes, int n_in,
                              void* d_out, int out_size, void* d_ws, size_t ws_size,
                              hipStream_t stream) {
  const float* c3 = (const float*)d_in[0];
  const float* c4 = (const float*)d_in[1];
  const float* c5 = (const float*)d_in[2];
  const float* smooth_w = (const float*)d_in[24];
  const float* smg = (const float*)d_in[25];
  const float* smb = (const float*)d_in[26];
  float* dout = (float*)d_out;

  char* wsb = (char*)d_ws;
  // region A (25,165,824 B): Xt3 during phase 1, cat afterwards (disjoint lifetimes)
  u16* Xt3 = (u16*)wsb;
  u16* cat = (u16*)wsb;
  u16* Wb  = (u16*)(wsb + 25165824);             // 14,155,776 B (branch packs, then smooth)
  float* Qt = (float*)(wsb + 39321600);          //  1,048,576 B
  float* sm = (float*)(wsb + 40370176);          //  1,048,576 B small pool
  float* Qs   = sm;             // 64
  float* Ck   = sm + 64;        // 32
  float* Mb   = sm + 128;       // 16384
  float* Mp   = sm + 16512;     // 131072
  float* Graw = sm + 147584;    // 16384
  float* EG   = sm + 163968;    // 32768
  float* ABf  = sm + 196736;    // 16384
  float* stat = sm + 213120;    // 1024
  float2* AB = (float2*)ABf;
  float* X3 = (float*)(wsb + 41418752);          // 25,165,824 B (3 branch conv outs)
  char* slab = wsb + 66584576;                   // 50,331,648 B (bslab bf16 / sslab f32)
  u16* bslab = (u16*)slab;
  float* sslab = (float*)slab;

  // ---- phase 1: batched branch convs (branch order: 0=x_8(c5), 1=x_16(c4), 2=x_32(c3))
  t_chwc3_k<<<dim3(16, 16, 6), 256, 0, stream>>>(c5, c4, c3, Xt3);
  wpack_k<512, 256><<<dim3(256, 3), 256, 0, stream>>>(
      (const float*)d_in[17], (const float*)d_in[10], (const float*)d_in[3], Wb);
  convsp_k<512, 256, 4, true><<<dim3(512, 3), 256, 0, stream>>>(Xt3, Wb, bslab);
  breduce_k<<<3072, 256, 0, stream>>>(bslab, X3);

  // ---- phase 2: per-branch tails (write cat; Xt3 is dead now)
  const size_t XEL = (size_t)2 * DCH * HWN;
  run_tail<8>(c5, d_in + 17, cat, 0,    X3,           Qt, Qs, Ck, Mb, Mp, Graw, EG, AB, stream);
  run_tail<16>(c4, d_in + 10, cat, 512, X3 + XEL,     Qt, Qs, Ck, Mb, Mp, Graw, EG, AB, stream);
  run_tail<32>(c3, d_in + 3, cat, 1024, X3 + 2 * XEL, Qt, Qs, Ck, Mb, Mp, Graw, EG, AB, stream);

  // ---- phase 3: smooth conv + BN2d + relu
  wpack_k<1536, 512><<<dim3(1536, 1), 256, 0, stream>>>(smooth_w, smooth_w, smooth_w, Wb);
  convsp_k<1536, 512, 3, false><<<dim3(768, 1), 256, 0, stream>>>(cat, Wb, sslab);
  sreduce_k<<<4096, 256, 0, stream>>>(sslab, dout);
  bnstat_k<<<512, 256, 0, stream>>>(dout, stat);
  bnrelu_k<<<16384, 256, 0, stream>>>(dout, stat, smg, smb);
}